// Round 11
// baseline (365.989 us; speedup 1.0000x reference)
//
#include <hip/hip_runtime.h>
#include <hip/hip_bf16.h>

typedef __attribute__((ext_vector_type(8))) short short8;
typedef __attribute__((ext_vector_type(4))) float f32x4;
typedef __attribute__((ext_vector_type(4))) int i32x4;

#define NTOK 576
#define DIM  1024
#define NB   4
#define NH   8
#define HD   128
#define KDIR 8
#define KN   4608
#define NSPLIT 4
#define NT 18                 // KN/NSPLIT/64

__device__ __forceinline__ float us2f(unsigned short u) {
    unsigned int x = ((unsigned int)u) << 16;
    return __uint_as_float(x);
}
__device__ __forceinline__ unsigned short f2us(float f) {
    unsigned int x = __float_as_uint(f);
    unsigned int r = x + 0x7fffu + ((x >> 16) & 1u);
    return (unsigned short)(r >> 16);
}

typedef __attribute__((address_space(3))) unsigned int lds_uint;
typedef const __attribute__((address_space(1))) unsigned int glb_uint;
__device__ __forceinline__ void async16(const unsigned short* g, unsigned short* l) {
    __builtin_amdgcn_global_load_lds((glb_uint*)g, (lds_uint*)l, 16, 0, 0);
}
__device__ __forceinline__ void wait_vm0_barrier() {
    asm volatile("s_waitcnt vmcnt(0)" ::: "memory");
    __builtin_amdgcn_s_barrier();
    __builtin_amdgcn_sched_barrier(0);
}

// meta[0] = 1 if device buffers are bf16, 0 if f32
__global__ void detect_kernel(const unsigned int* __restrict__ src, int* meta)
{
    if (threadIdx.x == 0) {
        int cnt = 0;
        for (int i = 0; i < 256; ++i) {
            unsigned u = src[(long)i * 16384] & 0xFFFFu;
            unsigned e = (u >> 7) & 0xFFu;
            cnt += (e >= 90 && e <= 150) ? 1 : 0;
        }
        meta[0] = (cnt >= 192) ? 1 : 0;
    }
}

// All 10 small conversions in one launch.
struct ConvJobs {
    const void* src[10];
    unsigned short* dst[10];
    int n4[10];
    int bstart[10];
};
__global__ __launch_bounds__(256)
void conv_all(ConvJobs J, const int* __restrict__ meta)
{
    const int b = blockIdx.x;
    int ji = 0;
    #pragma unroll
    for (int i = 1; i < 10; ++i) if (b >= J.bstart[i]) ji = i;
    const long base = (long)(b - J.bstart[ji]) * 1024 + threadIdx.x;
    const long n4 = J.n4[ji];
    if (meta[0]) {
        const ushort4* s = (const ushort4*)J.src[ji];
        ushort4* d = (ushort4*)J.dst[ji];
        #pragma unroll
        for (int t = 0; t < 4; ++t) {
            long i = base + t * 256;
            if (i < n4) d[i] = s[i];
        }
    } else {
        const float4* s = (const float4*)J.src[ji];
        ushort4* d = (ushort4*)J.dst[ji];
        #pragma unroll
        for (int t = 0; t < 4; ++t) {
            long i = base + t * 256;
            if (i < n4) {
                float4 v = s[i];
                ushort4 o;
                o.x = f2us(v.x); o.y = f2us(v.y); o.z = f2us(v.z); o.w = f2us(v.w);
                d[i] = o;
            }
        }
    }
}

// dirW [8][1024 d][1024 e] -> dWT [8][1024 e][1024 d]
__global__ __launch_bounds__(256)
void transpose_conv(const void* __restrict__ src, unsigned short* __restrict__ dst,
                    const int* __restrict__ meta)
{
    const int k = blockIdx.y;
    const int ty = blockIdx.x >> 5, tx = blockIdx.x & 31;
    const int d0 = ty * 32, e0 = tx * 32;
    __shared__ float tl[32][33];
    const int t = threadIdx.x;
    const int row = t >> 3, c4 = (t & 7) * 4;
    const long sbase = ((long)k * 1024 + d0 + row) * 1024 + e0 + c4;
    if (meta[0]) {
        const unsigned short* s = (const unsigned short*)src;
        ushort4 v = *(const ushort4*)(s + sbase);
        tl[row][c4+0] = us2f(v.x); tl[row][c4+1] = us2f(v.y);
        tl[row][c4+2] = us2f(v.z); tl[row][c4+3] = us2f(v.w);
    } else {
        const float* s = (const float*)src;
        float4 v = *(const float4*)(s + sbase);
        tl[row][c4+0] = v.x; tl[row][c4+1] = v.y;
        tl[row][c4+2] = v.z; tl[row][c4+3] = v.w;
    }
    __syncthreads();
    ushort4 o;
    o.x = f2us(tl[c4+0][row]); o.y = f2us(tl[c4+1][row]);
    o.z = f2us(tl[c4+2][row]); o.w = f2us(tl[c4+3][row]);
    *(ushort4*)(dst + ((long)k * 1024 + e0 + row) * 1024 + d0 + c4) = o;
}

// 128x128 single-buffer m97-structure GEMM (kept for dirs+Q and out/fin).
// MODE: 0 row-major C; 6 merged dirs(z<8)+Q(z==8, pre-scaled by 1/sqrt(128)*log2e)
template<int MODE, int TN, int BM, int BN>
__global__ __launch_bounds__(256)
void gemm_glds(const unsigned short* __restrict__ A, const unsigned short* __restrict__ Bw,
               const unsigned short* __restrict__ bias, unsigned short* __restrict__ C,
               const unsigned short* __restrict__ B2, const unsigned short* __restrict__ bias2,
               unsigned short* __restrict__ C2,
               int M, long bStride, long biasStride)
{
    constexpr int MI = BM / 32, NI = BN / 32;
    const int z = blockIdx.y;
    const unsigned short* Bb;
    const unsigned short* Gb;
    if constexpr (MODE == 6) {
        Bb = (z < 8) ? Bw + (long)z * bStride : B2;
        Gb = (z < 8) ? bias + (long)z * biasStride : bias2;
    } else {
        Bb = Bw + (long)z * bStride;
        Gb = bias + (long)z * biasStride;
    }
    const int tm = blockIdx.x / TN;
    const int tn = blockIdx.x % TN;

    __shared__ __align__(16) unsigned short As[BM * 64];
    __shared__ __align__(16) unsigned short Bs[BN * 64];

    const int tid = threadIdx.x, lane = tid & 63, wid = tid >> 6;
    const int wm = wid >> 1, wn = wid & 1;
    const int r0 = lane & 15, hi = lane >> 4;
    const int lr = lane >> 3;
    const int lg = lane & 7;

    f32x4 zz = {0.f, 0.f, 0.f, 0.f};
    f32x4 acc[MI][NI];
    #pragma unroll
    for (int i = 0; i < MI; ++i)
        #pragma unroll
        for (int j = 0; j < NI; ++j) acc[i][j] = zz;

    const int sgc = ((lg ^ (lr & 7)) << 3);

    for (int k0 = 0; k0 < 1024; k0 += 64) {
        #pragma unroll
        for (int j = 0; j < BM / 32; ++j) {
            int rb = wid * (BM / 4) + j * 8;
            async16(A + (long)(tm * BM + rb + lr) * 1024 + k0 + sgc, &As[rb * 64]);
        }
        #pragma unroll
        for (int j = 0; j < BN / 32; ++j) {
            int rb = wid * (BN / 4) + j * 8;
            async16(Bb + (long)(tn * BN + rb + lr) * 1024 + k0 + sgc, &Bs[rb * 64]);
        }
        __syncthreads();
        __builtin_amdgcn_s_setprio(1);
        #pragma unroll
        for (int kd = 0; kd < 2; ++kd) {
            const int pg = ((kd * 4 + hi) ^ (r0 & 7)) << 3;
            short8 af[MI], bfr[NI];
            #pragma unroll
            for (int mi = 0; mi < MI; ++mi)
                af[mi] = *reinterpret_cast<const short8*>(&As[(wm * (BM/2) + mi * 16 + r0) * 64 + pg]);
            #pragma unroll
            for (int ni = 0; ni < NI; ++ni)
                bfr[ni] = *reinterpret_cast<const short8*>(&Bs[(wn * (BN/2) + ni * 16 + r0) * 64 + pg]);
            #pragma unroll
            for (int mi = 0; mi < MI; ++mi)
                #pragma unroll
                for (int ni = 0; ni < NI; ++ni)
                    acc[mi][ni] = __builtin_amdgcn_mfma_f32_16x16x32_bf16(af[mi], bfr[ni], acc[mi][ni], 0, 0, 0);
        }
        __builtin_amdgcn_s_setprio(0);
        __syncthreads();
    }

    const float QSCL = 0.08838834764831845f * 1.4426950408889634f;
    const int jr = hi * 4;
    #pragma unroll
    for (int ni = 0; ni < NI; ++ni) {
        int cg = tn * BN + wn * (BN/2) + ni * 16 + r0;
        float bv = us2f(Gb[cg]);
        #pragma unroll
        for (int mi = 0; mi < MI; ++mi) {
            #pragma unroll
            for (int j = 0; j < 4; ++j) {
                int rg = tm * BM + wm * (BM/2) + mi * 16 + jr + j;
                float val = acc[mi][ni][j] + bv;
                if constexpr (MODE == 0) {
                    C[(long)rg * 1024 + cg] = f2us(val);
                } else {  // MODE 6
                    int b = rg / 576, n = rg - b * 576;
                    if (z == 8) {
                        int h = cg >> 7, d = cg & 127;
                        C2[((long)(b * 8 + h) * 576 + n) * 128 + d] = f2us(val * QSCL);
                    } else {
                        C[((long)b * 4608 + (long)z * 576 + n) * 1024 + cg] = f2us(val);
                    }
                }
            }
        }
    }
}

// 256x256 8-wave counted-vmcnt KV GEMM (T3+T4 structure).
// C = dirs[18432 x 1024] @ (wk||wv)^T + bias. tn<4 -> Kh [bh][kv][128];
// tn>=4 -> VTh [bh][128][4608] phi-permuted. 4 phases/K-tile, stage A in ph0 /
// B in ph1, vmcnt(4) counted wait (loads stay in flight across the boundary).
__global__ __launch_bounds__(512, 1)
void gemm_kv8(const unsigned short* __restrict__ A, const unsigned short* __restrict__ Bw,
              const unsigned short* __restrict__ bias, unsigned short* __restrict__ Kh,
              unsigned short* __restrict__ VTh)
{
    const int tm = blockIdx.x >> 3;
    const int tn = blockIdx.x & 7;

    __shared__ __align__(16) unsigned short As[2][256 * 64];
    __shared__ __align__(16) unsigned short Bs[2][256 * 64];

    const int tid = threadIdx.x, lane = tid & 63, wid = tid >> 6;
    const int wm = wid >> 2, wn = wid & 3;
    const int r0 = lane & 15, hi = lane >> 4;

    // staging: round r covers rows r*64 + (tid>>3), group tid&7 (XOR-swizzled src)
    const int srow = tid >> 3;
    const int sgc  = (((tid & 7) ^ (srow & 7)) << 3);
    const long abase = (long)(tm * 256 + srow) * 1024 + sgc;
    const long bbase = (long)(tn * 256 + srow) * 1024 + sgc;
    const int  ldst  = wid * 512;   // ushort offset of this wave's chunk in round 0

    f32x4 zz = {0.f, 0.f, 0.f, 0.f};
    f32x4 acc[8][4];
    #pragma unroll
    for (int i = 0; i < 8; ++i)
        #pragma unroll
        for (int j = 0; j < 4; ++j) acc[i][j] = zz;

    auto stageA = [&](int kt, int buf) {
        #pragma unroll
        for (int r = 0; r < 4; ++r)
            async16(A + abase + (long)r * 65536 + kt * 64, &As[buf][r * 4096 + ldst]);
    };
    auto stageB = [&](int kt, int buf) {
        #pragma unroll
        for (int r = 0; r < 4; ++r)
            async16(Bw + bbase + (long)r * 65536 + kt * 64, &Bs[buf][r * 4096 + ldst]);
    };

    stageA(0, 0);
    stageB(0, 0);

    const int arow0 = wm * 128 + r0;
    const int brow0 = wn * 64 + r0;
    const int pg0 = ((hi ^ (r0 & 7)) << 3);
    const int pg1 = (((4 + hi) ^ (r0 & 7)) << 3);

    for (int kt = 0; kt < 16; ++kt) {
        const unsigned short* Ac = As[kt & 1];
        const unsigned short* Bc = Bs[kt & 1];
        __builtin_amdgcn_s_barrier();          // all waves done reading buf[(kt+1)&1]
        if (kt < 15) {
            stageA(kt + 1, (kt + 1) & 1);      // issue next A (4 loads) -> 12 outstanding
            asm volatile("s_waitcnt vmcnt(4)" ::: "memory");  // tile kt landed; next-A in flight
        } else {
            asm volatile("s_waitcnt vmcnt(0)" ::: "memory");
        }
        __builtin_amdgcn_sched_barrier(0);

        #pragma unroll
        for (int q = 0; q < 4; ++q) {
            if (q == 1 && kt < 15) stageB(kt + 1, (kt + 1) & 1);
            short8 af[2][2], bf[4][2];
            #pragma unroll
            for (int dm = 0; dm < 2; ++dm) {
                const int row = (arow0 + (q * 2 + dm) * 16) * 64;
                af[dm][0] = *reinterpret_cast<const short8*>(&Ac[row + pg0]);
                af[dm][1] = *reinterpret_cast<const short8*>(&Ac[row + pg1]);
            }
            #pragma unroll
            for (int ni = 0; ni < 4; ++ni) {
                const int row = (brow0 + ni * 16) * 64;
                bf[ni][0] = *reinterpret_cast<const short8*>(&Bc[row + pg0]);
                bf[ni][1] = *reinterpret_cast<const short8*>(&Bc[row + pg1]);
            }
            __builtin_amdgcn_s_setprio(1);
            #pragma unroll
            for (int dm = 0; dm < 2; ++dm)
                #pragma unroll
                for (int ni = 0; ni < 4; ++ni) {
                    acc[q*2+dm][ni] = __builtin_amdgcn_mfma_f32_16x16x32_bf16(af[dm][0], bf[ni][0], acc[q*2+dm][ni], 0, 0, 0);
                    acc[q*2+dm][ni] = __builtin_amdgcn_mfma_f32_16x16x32_bf16(af[dm][1], bf[ni][1], acc[q*2+dm][ni], 0, 0, 0);
                }
            __builtin_amdgcn_s_setprio(0);
            __builtin_amdgcn_sched_barrier(0);
        }
    }

    const int jr = hi * 4;
    if (tn < 4) {
        // K half -> Kh [bh][kv][128]
        #pragma unroll
        for (int ni = 0; ni < 4; ++ni) {
            int cg = tn * 256 + wn * 64 + ni * 16 + r0;
            float bv = us2f(bias[cg]);
            int h = cg >> 7, d = cg & 127;
            #pragma unroll
            for (int mi = 0; mi < 8; ++mi) {
                #pragma unroll
                for (int j = 0; j < 4; ++j) {
                    int rg = tm * 256 + wm * 128 + mi * 16 + jr + j;
                    int b = rg / 4608, kv = rg - b * 4608;
                    Kh[((long)(b * 8 + h) * 4608 + kv) * 128 + d] = f2us(acc[mi][ni][j] + bv);
                }
            }
        }
    } else {
        // V half -> VTh [bh][128][4608], kv phi-permuted within each 64-block
        #pragma unroll
        for (int ni = 0; ni < 4; ++ni) {
            int cgr = tn * 256 + wn * 64 + ni * 16 + r0;
            float bv = us2f(bias[cgr]);
            int cg = cgr - 1024;
            int h = cg >> 7, d = cg & 127;
            #pragma unroll
            for (int mi = 0; mi < 8; ++mi) {
                int rgb = tm * 256 + wm * 128 + mi * 16 + jr;
                int b = rgb / 4608, kv = rgb - b * 4608;
                int r = kv & 63;
                int P = ((r >> 5) & 1) * 32 + ((r >> 3) & 1) * 16 + ((r >> 2) & 1) * 8
                      + ((r >> 4) & 1) * 4 + (r & 3);
                ushort4 o;
                o.x = f2us(acc[mi][ni][0] + bv);
                o.y = f2us(acc[mi][ni][1] + bv);
                o.z = f2us(acc[mi][ni][2] + bv);
                o.w = f2us(acc[mi][ni][3] + bv);
                *(ushort4*)&VTh[((long)(b * 8 + h) * 128 + d) * 4608 + (kv & ~63) + P] = o;
            }
        }
    }
}

// 3-chunk swapped-operand flash attention (unchanged from round 10).
__global__ __launch_bounds__(256, 2)
void attn_kernel7(const unsigned short* __restrict__ Qh, const unsigned short* __restrict__ Kh,
                  const unsigned short* __restrict__ VTh, unsigned short* __restrict__ Opart,
                  float2* __restrict__ Ml)
{
    const int bid = blockIdx.x;
    const int logical = (bid & 7) * 48 + (bid >> 3);   // 384 blocks, XCD-grouped
    const int bhsp = logical / 3;
    const int qt = logical - bhsp * 3;
    const int bh = bhsp >> 2;
    const int sp = bhsp & 3;

    const int tid = threadIdx.x;
    const int lane = tid & 63, wid = tid >> 6;
    const int r0 = lane & 15, hi = lane >> 4;

    __shared__ __align__(16) unsigned short Ks[2][64 * 128];
    __shared__ __align__(16) unsigned short VT[2][128 * 64];

    short8 qf[3][4];
    #pragma unroll
    for (int c = 0; c < 3; ++c) {
        const long qoff = ((long)bh * NTOK + qt * 192 + c * 64 + wid * 16 + r0) * HD + hi * 8;
        #pragma unroll
        for (int kd = 0; kd < 4; ++kd)
            qf[c][kd] = *reinterpret_cast<const short8*>(Qh + qoff + kd * 32);
    }

    f32x4 zz = {0.f, 0.f, 0.f, 0.f};
    f32x4 oacc[3][8];
    #pragma unroll
    for (int c = 0; c < 3; ++c)
        #pragma unroll
        for (int i = 0; i < 8; ++i) oacc[c][i] = zz;
    float mrun[3], lrun[3];
    #pragma unroll
    for (int c = 0; c < 3; ++c) { mrun[c] = -1e30f; lrun[c] = 0.f; }

    int offK[4], offV[4];
    #pragma unroll
    for (int j = 0; j < 4; ++j) {
        offK[j] = (wid * 16 + 4 * j + hi) * 128 + (((lane & 15) ^ ((4 * j + hi) & 7)) << 3);
        offV[j] = (wid * 32 + 8 * j + (lane >> 3)) * KN + (((lane & 7) ^ (lane >> 3)) << 3);
    }
    const unsigned short* kp = Kh + (long)bh * KN * HD + (long)(sp * (KN / NSPLIT)) * HD;
    const unsigned short* vp = VTh + (long)bh * HD * KN + sp * (KN / NSPLIT);

    auto stage = [&](int buf) {
        #pragma unroll
        for (int j = 0; j < 4; ++j) {
            async16(kp + offK[j], &Ks[buf][(wid * 16 + 4 * j) * 128]);
            async16(vp + offV[j], &VT[buf][(wid * 32 + 8 * j) * 64]);
        }
    };

    stage(0);
    for (int kt = 0; kt < NT; ++kt) {
        wait_vm0_barrier();
        if (kt < NT - 1) { kp += 64 * HD; vp += 64; stage((kt + 1) & 1); }
        const unsigned short* Ksb = Ks[kt & 1];
        const unsigned short* VTb = VT[kt & 1];

        f32x4 s[3][4];
        #pragma unroll
        for (int c = 0; c < 3; ++c)
            #pragma unroll
            for (int nb = 0; nb < 4; ++nb) s[c][nb] = zz;
        __builtin_amdgcn_s_setprio(1);
        #pragma unroll
        for (int nb = 0; nb < 4; ++nb) {
            #pragma unroll
            for (int kd = 0; kd < 4; ++kd) {
                short8 kf = *reinterpret_cast<const short8*>(
                    &Ksb[(nb * 16 + r0) * 128 + (((kd * 4 + hi) ^ (r0 & 7)) << 3)]);
                s[0][nb] = __builtin_amdgcn_mfma_f32_16x16x32_bf16(kf, qf[0][kd], s[0][nb], 0, 0, 0);
                s[1][nb] = __builtin_amdgcn_mfma_f32_16x16x32_bf16(kf, qf[1][kd], s[1][nb], 0, 0, 0);
                s[2][nb] = __builtin_amdgcn_mfma_f32_16x16x32_bf16(kf, qf[2][kd], s[2][nb], 0, 0, 0);
            }
        }
        __builtin_amdgcn_s_setprio(0);

        unsigned pk0[3][4], pk1[3][4];
        #pragma unroll
        for (int c = 0; c < 3; ++c) {
            float mt = fmaxf(fmaxf(fmaxf(s[c][0][0], s[c][0][1]), fmaxf(s[c][0][2], s[c][0][3])),
                       fmaxf(fmaxf(fmaxf(s[c][1][0], s[c][1][1]), fmaxf(s[c][1][2], s[c][1][3])),
                       fmaxf(fmaxf(fmaxf(s[c][2][0], s[c][2][1]), fmaxf(s[c][2][2], s[c][2][3])),
                             fmaxf(fmaxf(s[c][3][0], s[c][3][1]), fmaxf(s[c][3][2], s[c][3][3])))));
            if (!__all(mt - mrun[c] <= 8.0f)) {
                float mr = fmaxf(mt, __shfl_xor(mt, 16));
                mr = fmaxf(mr, __shfl_xor(mr, 32));
                float mn = fmaxf(mrun[c], mr);
                float scl = exp2f(mrun[c] - mn);
                mrun[c] = mn;
                lrun[c] *= scl;
                #pragma unroll
                for (int db = 0; db < 8; ++db)
                    #pragma unroll
                    for (int j = 0; j < 4; ++j)
                        oacc[c][db][j] *= scl;
            }
            float rt = 0.f;
            #pragma unroll
            for (int nb = 0; nb < 4; ++nb)
                #pragma unroll
                for (int j = 0; j < 4; ++j) {
                    s[c][nb][j] = exp2f(s[c][nb][j] - mrun[c]);
                    rt += s[c][nb][j];
                }
            lrun[c] += rt;
            #pragma unroll
            for (int nb = 0; nb < 4; ++nb) {
                asm("v_cvt_pk_bf16_f32 %0, %1, %2" : "=v"(pk0[c][nb]) : "v"(s[c][nb][0]), "v"(s[c][nb][1]));
                asm("v_cvt_pk_bf16_f32 %0, %1, %2" : "=v"(pk1[c][nb]) : "v"(s[c][nb][2]), "v"(s[c][nb][3]));
            }
        }

        __builtin_amdgcn_s_setprio(1);
        #pragma unroll
        for (int kd = 0; kd < 2; ++kd) {
            short8 pf[3];
            #pragma unroll
            for (int c = 0; c < 3; ++c) {
                i32x4 fr;
                fr[0] = (int)pk0[c][2 * kd];
                fr[1] = (int)pk1[c][2 * kd];
                fr[2] = (int)pk0[c][2 * kd + 1];
                fr[3] = (int)pk1[c][2 * kd + 1];
                pf[c] = *reinterpret_cast<short8*>(&fr);
            }
            #pragma unroll
            for (int db = 0; db < 8; ++db) {
                short8 vf = *reinterpret_cast<const short8*>(
                    &VTb[(db * 16 + r0) * 64 + (((kd * 4 + hi) ^ (r0 & 7)) << 3)]);
                oacc[0][db] = __builtin_amdgcn_mfma_f32_16x16x32_bf16(vf, pf[0], oacc[0][db], 0, 0, 0);
                oacc[1][db] = __builtin_amdgcn_mfma_f32_16x16x32_bf16(vf, pf[1], oacc[1][db], 0, 0, 0);
                oacc[2][db] = __builtin_amdgcn_mfma_f32_16x16x32_bf16(vf, pf[2], oacc[2][db], 0, 0, 0);
            }
        }
        __builtin_amdgcn_s_setprio(0);
    }

    #pragma unroll
    for (int c = 0; c < 3; ++c) {
        float lr = lrun[c];
        lr += __shfl_xor(lr, 16);
        lr += __shfl_xor(lr, 32);
        const float inv = 1.f / lr;
        const long po = ((long)(sp * 32 + bh) * NTOK + qt * 192 + c * 64 + wid * 16 + r0) * HD;
        #pragma unroll
        for (int db = 0; db < 8; ++db) {
            ushort4 o;
            o.x = f2us(oacc[c][db][0] * inv);
            o.y = f2us(oacc[c][db][1] * inv);
            o.z = f2us(oacc[c][db][2] * inv);
            o.w = f2us(oacc[c][db][3] * inv);
            *(ushort4*)&Opart[po + db * 16 + hi * 4] = o;
        }
        if (lane < 16) {
            const long mo = (long)(sp * 32 + bh) * NTOK + qt * 192 + c * 64 + wid * 16 + r0;
            Ml[mo] = make_float2(mrun[c], lr);
        }
    }
}

// Combine NSPLIT partials -> Ob[(b*576+n)*1024 + h*128 + d]
__global__ __launch_bounds__(256)
void attn_reduce(const unsigned short* __restrict__ Opart, const float2* __restrict__ Ml,
                 unsigned short* __restrict__ Ob)
{
    const int qt = blockIdx.x, bh = blockIdx.y;
    const int t = threadIdx.x;
    const int rl = t >> 2, dc = (t & 3) * 32;
    const int q = qt * 64 + rl;

    float m[NSPLIT], l[NSPLIT];
    float M = -1e30f;
    #pragma unroll
    for (int sp = 0; sp < NSPLIT; ++sp) {
        float2 v = Ml[(long)(sp * 32 + bh) * NTOK + q];
        m[sp] = v.x; l[sp] = v.y;
        M = fmaxf(M, v.x);
    }
    float w[NSPLIT], denom = 0.f;
    #pragma unroll
    for (int sp = 0; sp < NSPLIT; ++sp) {
        w[sp] = l[sp] * exp2f(m[sp] - M);
        denom += w[sp];
    }
    const float inv = 1.f / denom;
    const int b = bh >> 3, h = bh & 7;
    #pragma unroll
    for (int dj = 0; dj < 4; ++dj) {
        float a[8];
        #pragma unroll
        for (int e = 0; e < 8; ++e) a[e] = 0.f;
        #pragma unroll
        for (int sp = 0; sp < NSPLIT; ++sp) {
            short8 v = *reinterpret_cast<const short8*>(
                &Opart[((long)(sp * 32 + bh) * NTOK + q) * HD + dc + dj * 8]);
            #pragma unroll
            for (int e = 0; e < 8; ++e)
                a[e] += w[sp] * us2f((unsigned short)v[e]);
        }
        short8 o;
        #pragma unroll
        for (int e = 0; e < 8; ++e) o[e] = (short)f2us(a[e] * inv);
        *reinterpret_cast<short8*>(&Ob[((long)b * NTOK + q) * 1024 + h * 128 + dc + dj * 8]) = o;
    }
}

// LayerNorm(y)*g + b + vision; output dtype per meta[0]
__global__ __launch_bounds__(256)
void ln2_kernel(const unsigned short* __restrict__ Y, const unsigned short* __restrict__ g,
                const unsigned short* __restrict__ be, const unsigned short* __restrict__ vis,
                void* __restrict__ dout, const int* __restrict__ meta)
{
    const int row = blockIdx.x;
    const int tid = threadIdx.x;
    const int lane = tid & 63, wid = tid >> 6;
    const unsigned short* yr = Y + (long)row * DIM;
    ushort4 raw = reinterpret_cast<const ushort4*>(yr)[tid];
    float v[4];
    v[0] = us2f(raw.x); v[1] = us2f(raw.y); v[2] = us2f(raw.z); v[3] = us2f(raw.w);
    float s1 = 0.f, s2 = 0.f;
    #pragma unroll
    for (int i = 0; i < 4; ++i) { s1 += v[i]; s2 += v[i] * v[i]; }
    #pragma unroll
    for (int off = 1; off < 64; off <<= 1) {
        s1 += __shfl_xor(s1, off);
        s2 += __shfl_xor(s2, off);
    }
    __shared__ float red[2][4];
    if (lane == 0) { red[0][wid] = s1; red[1][wid] = s2; }
    __syncthreads();
    s1 = red[0][0] + red[0][1] + red[0][2] + red[0][3];
    s2 = red[1][0] + red[1][1] + red[1][2] + red[1][3];
    const float mu = s1 * (1.f / DIM);
    const float var = s2 * (1.f / DIM) - mu * mu;
    const float inv = rsqrtf(var + 1e-5f);
    ushort4 gg = reinterpret_cast<const ushort4*>(g)[tid];
    ushort4 bb = reinterpret_cast<const ushort4*>(be)[tid];
    ushort4 vv = reinterpret_cast<const ushort4*>(vis + (long)row * DIM)[tid];
    float o0 = (v[0] - mu) * inv * us2f(gg.x) + us2f(bb.x) + us2f(vv.x);
    float o1 = (v[1] - mu) * inv * us2f(gg.y) + us2f(bb.y) + us2f(vv.y);
    float o2 = (v[2] - mu) * inv * us2f(gg.z) + us2f(bb.z) + us2f(vv.z);
    float o3 = (v[3] - mu) * inv * us2f(gg.w) + us2f(bb.w) + us2f(vv.w);
    if (meta[0]) {
        ushort4 o;
        o.x = f2us(o0); o.y = f2us(o1); o.z = f2us(o2); o.w = f2us(o3);
        reinterpret_cast<ushort4*>((unsigned short*)dout + (long)row * DIM)[tid] = o;
    } else {
        float4 o = make_float4(o0, o1, o2, o3);
        reinterpret_cast<float4*>((float*)dout + (long)row * DIM)[tid] = o;
    }
}

extern "C" void kernel_launch(void* const* d_in, const int* in_sizes, int n_in,
                              void* d_out, int out_size, void* d_ws, size_t ws_size,
                              hipStream_t stream)
{
    // scan_idx (d_in[11]) unused: all 8 scans are bijections on the 576 cells and
    // softmax over the full K*N key axis (K,V share row order) is permutation-
    // invariant per direction block -> gather elided.
    unsigned long long w = (unsigned long long)d_ws;
    int* meta = (int*)w; w += 256;

    const int cidx[10] = {0, 2, 3, 4, 5, 6, 7, 8, 9, 10};
    const long csz[10] = {
        (long)NB * NTOK * DIM,  // vision
        (long)KDIR * DIM,       // dirb
        3L * DIM * DIM,         // inW
        3L * DIM,               // inB
        (long)DIM * DIM,        // outW
        DIM,                    // outB
        (long)DIM * DIM,        // finW
        DIM, DIM, DIM           // finB, lng, lnb
    };
    unsigned short* cv[10];
    for (int i = 0; i < 10; ++i) {
        cv[i] = (unsigned short*)w;
        w += (csz[i] * 2 + 255) & ~255ULL;
    }
    unsigned short* dWT = (unsigned short*)w; w += (long)KDIR * DIM * DIM * 2;

    const size_t big = (size_t)NB * KDIR * NTOK * DIM * 2;   // 37.75 MB
    const size_t sml = (size_t)NB * NTOK * DIM * 2;          // 4.72 MB
    unsigned short* dirs = (unsigned short*)w; w += big;     // aliased as Opart later
    unsigned short* Kh   = (unsigned short*)w; w += big;
    unsigned short* VTh  = (unsigned short*)w; w += big;
    unsigned short* Qh   = (unsigned short*)w; w += sml;
    unsigned short* Ob   = (unsigned short*)w; w += sml;
    unsigned short* Fu   = (unsigned short*)w; w += sml;
    unsigned short* Y2   = (unsigned short*)w; w += sml;
    float2* Ml = (float2*)w; w += (long)NSPLIT * 32 * NTOK * sizeof(float2);
    unsigned short* Opart = dirs;   // dirs is dead once KV GEMM completes

    const unsigned short* vision = cv[0];
    const unsigned short* dirb = cv[1];
    const unsigned short* inW = cv[2];
    const unsigned short* inB = cv[3];
    const unsigned short* outW = cv[4];
    const unsigned short* outB = cv[5];
    const unsigned short* finW = cv[6];
    const unsigned short* finB = cv[7];
    const unsigned short* lng = cv[8];
    const unsigned short* lnbt = cv[9];

    dim3 blk(256, 1, 1);

    // 0. dtype detect
    detect_kernel<<<dim3(1), dim3(64), 0, stream>>>((const unsigned int*)d_in[1], meta);

    // 1. single fused conversion launch (+ transposed dirW)
    ConvJobs J;
    int bacc = 0;
    for (int i = 0; i < 10; ++i) {
        J.src[i] = d_in[cidx[i]];
        J.dst[i] = cv[i];
        J.n4[i] = (int)(csz[i] / 4);
        J.bstart[i] = bacc;
        bacc += (int)((csz[i] / 4 + 1023) / 1024);
    }
    conv_all<<<dim3(bacc), blk, 0, stream>>>(J, meta);
    transpose_conv<<<dim3(1024, KDIR), blk, 0, stream>>>(d_in[1], dWT, meta);

    // 2. merged dirs(z<8)+Q(z==8, pre-scaled) GEMM: A=vision, M=2304
    gemm_glds<6, 8, 128, 128><<<dim3(18 * 8, 9), blk, 0, stream>>>(
        vision, dWT, dirb, dirs, inW, inB, Qh, NB * NTOK, (long)DIM * DIM, DIM);

    // 3. fused K+V GEMM, 256^2 counted-vmcnt pipeline: K->Kh, V->VTh (phi-permuted)
    gemm_kv8<<<dim3(72 * 8), dim3(512), 0, stream>>>(
        dirs, inW + DIM * DIM, inB + DIM, Kh, VTh);

    // 4. 3-chunk KV-split flash attention -> Opart (aliases dirs) + Ml
    attn_kernel7<<<dim3(3 * 32 * NSPLIT), blk, 0, stream>>>(Qh, Kh, VTh, Opart, Ml);

    // 5. combine partials -> Ob [b,n,h*128+d]
    attn_reduce<<<dim3(9, 32), blk, 0, stream>>>(Opart, Ml, Ob);

    // 6. fused = Ob @ out_proj^T + b   (64x64 tile: 576 blocks)
    gemm_glds<0, 16, 64, 64><<<dim3(36 * 16, 1), blk, 0, stream>>>(
        Ob, outW, outB, Fu, nullptr, nullptr, nullptr, NB * NTOK, 0L, 0L);

    // 7. y = fused @ fin^T + b
    gemm_glds<0, 16, 64, 64><<<dim3(36 * 16, 1), blk, 0, stream>>>(
        Fu, finW, finB, Y2, nullptr, nullptr, nullptr, NB * NTOK, 0L, 0L);

    // 8. LayerNorm + residual -> d_out
    ln2_kernel<<<dim3(NB * NTOK), blk, 0, stream>>>(Y2, lng, lnbt, vision, d_out, meta);
}

// Round 12
// 344.748 us; speedup vs baseline: 1.0616x; 1.0616x over previous
//
#include <hip/hip_runtime.h>
#include <hip/hip_bf16.h>

typedef __attribute__((ext_vector_type(8))) short short8;
typedef __attribute__((ext_vector_type(4))) float f32x4;
typedef __attribute__((ext_vector_type(4))) int i32x4;

#define NTOK 576
#define DIM  1024
#define NB   4
#define NH   8
#define HD   128
#define KDIR 8
#define KN   4608
#define NSPLIT 6
#define NT 12                 // KN/NSPLIT/64

__device__ __forceinline__ float us2f(unsigned short u) {
    unsigned int x = ((unsigned int)u) << 16;
    return __uint_as_float(x);
}
__device__ __forceinline__ unsigned short f2us(float f) {
    unsigned int x = __float_as_uint(f);
    unsigned int r = x + 0x7fffu + ((x >> 16) & 1u);
    return (unsigned short)(r >> 16);
}

typedef __attribute__((address_space(3))) unsigned int lds_uint;
typedef const __attribute__((address_space(1))) unsigned int glb_uint;
__device__ __forceinline__ void async16(const unsigned short* g, unsigned short* l) {
    __builtin_amdgcn_global_load_lds((glb_uint*)g, (lds_uint*)l, 16, 0, 0);
}
__device__ __forceinline__ void wait_vm0_barrier() {
    asm volatile("s_waitcnt vmcnt(0)" ::: "memory");
    __builtin_amdgcn_s_barrier();
    __builtin_amdgcn_sched_barrier(0);
}

// meta[0] = 1 if device buffers are bf16, 0 if f32
__global__ void detect_kernel(const unsigned int* __restrict__ src, int* meta)
{
    if (threadIdx.x == 0) {
        int cnt = 0;
        for (int i = 0; i < 256; ++i) {
            unsigned u = src[(long)i * 16384] & 0xFFFFu;
            unsigned e = (u >> 7) & 0xFFu;
            cnt += (e >= 90 && e <= 150) ? 1 : 0;
        }
        meta[0] = (cnt >= 192) ? 1 : 0;
    }
}

// All 10 small conversions in one launch.
struct ConvJobs {
    const void* src[10];
    unsigned short* dst[10];
    int n4[10];
    int bstart[10];
};
__global__ __launch_bounds__(256)
void conv_all(ConvJobs J, const int* __restrict__ meta)
{
    const int b = blockIdx.x;
    int ji = 0;
    #pragma unroll
    for (int i = 1; i < 10; ++i) if (b >= J.bstart[i]) ji = i;
    const long base = (long)(b - J.bstart[ji]) * 1024 + threadIdx.x;
    const long n4 = J.n4[ji];
    if (meta[0]) {
        const ushort4* s = (const ushort4*)J.src[ji];
        ushort4* d = (ushort4*)J.dst[ji];
        #pragma unroll
        for (int t = 0; t < 4; ++t) {
            long i = base + t * 256;
            if (i < n4) d[i] = s[i];
        }
    } else {
        const float4* s = (const float4*)J.src[ji];
        ushort4* d = (ushort4*)J.dst[ji];
        #pragma unroll
        for (int t = 0; t < 4; ++t) {
            long i = base + t * 256;
            if (i < n4) {
                float4 v = s[i];
                ushort4 o;
                o.x = f2us(v.x); o.y = f2us(v.y); o.z = f2us(v.z); o.w = f2us(v.w);
                d[i] = o;
            }
        }
    }
}

// dirW [8][1024 d][1024 e] -> dWT [8][1024 e][1024 d]
__global__ __launch_bounds__(256)
void transpose_conv(const void* __restrict__ src, unsigned short* __restrict__ dst,
                    const int* __restrict__ meta)
{
    const int k = blockIdx.y;
    const int ty = blockIdx.x >> 5, tx = blockIdx.x & 31;
    const int d0 = ty * 32, e0 = tx * 32;
    __shared__ float tl[32][33];
    const int t = threadIdx.x;
    const int row = t >> 3, c4 = (t & 7) * 4;
    const long sbase = ((long)k * 1024 + d0 + row) * 1024 + e0 + c4;
    if (meta[0]) {
        const unsigned short* s = (const unsigned short*)src;
        ushort4 v = *(const ushort4*)(s + sbase);
        tl[row][c4+0] = us2f(v.x); tl[row][c4+1] = us2f(v.y);
        tl[row][c4+2] = us2f(v.z); tl[row][c4+3] = us2f(v.w);
    } else {
        const float* s = (const float*)src;
        float4 v = *(const float4*)(s + sbase);
        tl[row][c4+0] = v.x; tl[row][c4+1] = v.y;
        tl[row][c4+2] = v.z; tl[row][c4+3] = v.w;
    }
    __syncthreads();
    ushort4 o;
    o.x = f2us(tl[c4+0][row]); o.y = f2us(tl[c4+1][row]);
    o.z = f2us(tl[c4+2][row]); o.w = f2us(tl[c4+3][row]);
    *(ushort4*)(dst + ((long)k * 1024 + e0 + row) * 1024 + d0 + c4) = o;
}

// C = A[M x 1024] @ B^T + bias. Tile BM x BN, BK=64, SINGLE-buffer glds staging
// (m97 structure: 32KB LDS -> 5 blocks/CU; implicit wave-level overlap hides drain).
// MODE: 0 row-major C; 5 fused KV (cg<1024 -> Kh [bh][kv][128], else VTh [bh][128][4608]
//       with kv phi-permuted within each 64-block for the attn b128 PV reads);
//       6 merged dirs(z<8)+Q(z==8, pre-scaled by 1/sqrt(128)*log2e)
template<int MODE, int TN, int BM, int BN>
__global__ __launch_bounds__(256)
void gemm_glds(const unsigned short* __restrict__ A, const unsigned short* __restrict__ Bw,
               const unsigned short* __restrict__ bias, unsigned short* __restrict__ C,
               const unsigned short* __restrict__ B2, const unsigned short* __restrict__ bias2,
               unsigned short* __restrict__ C2,
               int M, long bStride, long biasStride)
{
    constexpr int MI = BM / 32, NI = BN / 32;
    const int z = blockIdx.y;
    const unsigned short* Bb;
    const unsigned short* Gb;
    if constexpr (MODE == 6) {
        Bb = (z < 8) ? Bw + (long)z * bStride : B2;
        Gb = (z < 8) ? bias + (long)z * biasStride : bias2;
    } else {
        Bb = Bw + (long)z * bStride;
        Gb = bias + (long)z * biasStride;
    }
    const int tm = blockIdx.x / TN;
    const int tn = blockIdx.x % TN;

    __shared__ __align__(16) unsigned short As[BM * 64];
    __shared__ __align__(16) unsigned short Bs[BN * 64];

    const int tid = threadIdx.x, lane = tid & 63, wid = tid >> 6;
    const int wm = wid >> 1, wn = wid & 1;
    const int r0 = lane & 15, hi = lane >> 4;
    const int lr = lane >> 3;
    const int lg = lane & 7;

    f32x4 zz = {0.f, 0.f, 0.f, 0.f};
    f32x4 acc[MI][NI];
    #pragma unroll
    for (int i = 0; i < MI; ++i)
        #pragma unroll
        for (int j = 0; j < NI; ++j) acc[i][j] = zz;

    const int sgc = ((lg ^ (lr & 7)) << 3);

    for (int k0 = 0; k0 < 1024; k0 += 64) {
        #pragma unroll
        for (int j = 0; j < BM / 32; ++j) {
            int rb = wid * (BM / 4) + j * 8;
            async16(A + (long)(tm * BM + rb + lr) * 1024 + k0 + sgc, &As[rb * 64]);
        }
        #pragma unroll
        for (int j = 0; j < BN / 32; ++j) {
            int rb = wid * (BN / 4) + j * 8;
            async16(Bb + (long)(tn * BN + rb + lr) * 1024 + k0 + sgc, &Bs[rb * 64]);
        }
        __syncthreads();
        __builtin_amdgcn_s_setprio(1);
        #pragma unroll
        for (int kd = 0; kd < 2; ++kd) {
            const int pg = ((kd * 4 + hi) ^ (r0 & 7)) << 3;
            short8 af[MI], bfr[NI];
            #pragma unroll
            for (int mi = 0; mi < MI; ++mi)
                af[mi] = *reinterpret_cast<const short8*>(&As[(wm * (BM/2) + mi * 16 + r0) * 64 + pg]);
            #pragma unroll
            for (int ni = 0; ni < NI; ++ni)
                bfr[ni] = *reinterpret_cast<const short8*>(&Bs[(wn * (BN/2) + ni * 16 + r0) * 64 + pg]);
            #pragma unroll
            for (int mi = 0; mi < MI; ++mi)
                #pragma unroll
                for (int ni = 0; ni < NI; ++ni)
                    acc[mi][ni] = __builtin_amdgcn_mfma_f32_16x16x32_bf16(af[mi], bfr[ni], acc[mi][ni], 0, 0, 0);
        }
        __builtin_amdgcn_s_setprio(0);
        __syncthreads();
    }

    const float QSCL = 0.08838834764831845f * 1.4426950408889634f;
    const int jr = hi * 4;
    #pragma unroll
    for (int ni = 0; ni < NI; ++ni) {
        int cg = tn * BN + wn * (BN/2) + ni * 16 + r0;
        float bv = us2f(Gb[cg]);
        if constexpr (MODE == 5) {
            if (cg >= 1024) {
                int cg2 = cg - 1024;
                int h = cg2 >> 7, d = cg2 & 127;
                #pragma unroll
                for (int mi = 0; mi < MI; ++mi) {
                    int rgb = tm * BM + wm * (BM/2) + mi * 16 + jr;
                    int b = rgb / 4608, kv = rgb - b * 4608;
                    // phi-permute kv within its 64-block: P = [b5][b3][b2][b4][b1b0]
                    int r = kv & 63;
                    int P = ((r >> 5) & 1) * 32 + ((r >> 3) & 1) * 16 + ((r >> 2) & 1) * 8
                          + ((r >> 4) & 1) * 4 + (r & 3);
                    ushort4 o;
                    o.x = f2us(acc[mi][ni][0] + bv);
                    o.y = f2us(acc[mi][ni][1] + bv);
                    o.z = f2us(acc[mi][ni][2] + bv);
                    o.w = f2us(acc[mi][ni][3] + bv);
                    *(ushort4*)&C2[((long)(b * 8 + h) * 128 + d) * 4608 + (kv & ~63) + P] = o;
                }
                continue;
            }
        }
        #pragma unroll
        for (int mi = 0; mi < MI; ++mi) {
            #pragma unroll
            for (int j = 0; j < 4; ++j) {
                int rg = tm * BM + wm * (BM/2) + mi * 16 + jr + j;
                float val = acc[mi][ni][j] + bv;
                if constexpr (MODE == 0) {
                    C[(long)rg * 1024 + cg] = f2us(val);
                } else if constexpr (MODE == 5) {
                    int b = rg / 4608, kv = rg - b * 4608;
                    int h = cg >> 7, d = cg & 127;
                    C[((long)(b * 8 + h) * 4608 + kv) * 128 + d] = f2us(val);
                } else {  // MODE 6
                    int b = rg / 576, n = rg - b * 576;
                    if (z == 8) {
                        int h = cg >> 7, d = cg & 127;
                        C2[((long)(b * 8 + h) * 576 + n) * 128 + d] = f2us(val * QSCL);
                    } else {
                        C[((long)b * 4608 + (long)z * 576 + n) * 1024 + cg] = f2us(val);
                    }
                }
            }
        }
    }
}

// 3-chunk swapped-operand flash attention: 192 q rows per block (48/wave).
// Each K/V LDS b128 read feeds 3 MFMAs (one per q-chunk) -> 3x LDS amortization.
// V^T global is phi-permuted so the PV A-fragment is one contiguous b128 and the
// P B-fragment is lane-local (zero shuffles, zero extra conflicts).
__global__ __launch_bounds__(256, 2)
void attn_kernel7(const unsigned short* __restrict__ Qh, const unsigned short* __restrict__ Kh,
                  const unsigned short* __restrict__ VTh, unsigned short* __restrict__ Opart,
                  float2* __restrict__ Ml)
{
    const int bid = blockIdx.x;
    const int logical = (bid & 7) * 72 + (bid >> 3);   // 576 blocks, XCD-grouped
    const int bhsp = logical / 3;
    const int qt = logical - bhsp * 3;                 // 0..2, 192-q tiles
    const int bh = bhsp / NSPLIT;
    const int sp = bhsp - bh * NSPLIT;

    const int tid = threadIdx.x;
    const int lane = tid & 63, wid = tid >> 6;
    const int r0 = lane & 15, hi = lane >> 4;

    __shared__ __align__(16) unsigned short Ks[2][64 * 128];
    __shared__ __align__(16) unsigned short VT[2][128 * 64];

    short8 qf[3][4];
    #pragma unroll
    for (int c = 0; c < 3; ++c) {
        const long qoff = ((long)bh * NTOK + qt * 192 + c * 64 + wid * 16 + r0) * HD + hi * 8;
        #pragma unroll
        for (int kd = 0; kd < 4; ++kd)
            qf[c][kd] = *reinterpret_cast<const short8*>(Qh + qoff + kd * 32);
    }

    f32x4 zz = {0.f, 0.f, 0.f, 0.f};
    f32x4 oacc[3][8];
    #pragma unroll
    for (int c = 0; c < 3; ++c)
        #pragma unroll
        for (int i = 0; i < 8; ++i) oacc[c][i] = zz;
    float mrun[3], lrun[3];
    #pragma unroll
    for (int c = 0; c < 3; ++c) { mrun[c] = -1e30f; lrun[c] = 0.f; }

    int offK[4], offV[4];
    #pragma unroll
    for (int j = 0; j < 4; ++j) {
        offK[j] = (wid * 16 + 4 * j + hi) * 128 + (((lane & 15) ^ ((4 * j + hi) & 7)) << 3);
        offV[j] = (wid * 32 + 8 * j + (lane >> 3)) * KN + (((lane & 7) ^ (lane >> 3)) << 3);
    }
    const unsigned short* kp = Kh + (long)bh * KN * HD + (long)(sp * (KN / NSPLIT)) * HD;
    const unsigned short* vp = VTh + (long)bh * HD * KN + sp * (KN / NSPLIT);

    auto stage = [&](int buf) {
        #pragma unroll
        for (int j = 0; j < 4; ++j) {
            async16(kp + offK[j], &Ks[buf][(wid * 16 + 4 * j) * 128]);
            async16(vp + offV[j], &VT[buf][(wid * 32 + 8 * j) * 64]);
        }
    };

    stage(0);
    for (int kt = 0; kt < NT; ++kt) {
        wait_vm0_barrier();
        if (kt < NT - 1) { kp += 64 * HD; vp += 64; stage((kt + 1) & 1); }
        const unsigned short* Ksb = Ks[kt & 1];
        const unsigned short* VTb = VT[kt & 1];

        // QK: each kf read feeds 3 MFMAs
        f32x4 s[3][4];
        #pragma unroll
        for (int c = 0; c < 3; ++c)
            #pragma unroll
            for (int nb = 0; nb < 4; ++nb) s[c][nb] = zz;
        __builtin_amdgcn_s_setprio(1);
        #pragma unroll
        for (int nb = 0; nb < 4; ++nb) {
            #pragma unroll
            for (int kd = 0; kd < 4; ++kd) {
                short8 kf = *reinterpret_cast<const short8*>(
                    &Ksb[(nb * 16 + r0) * 128 + (((kd * 4 + hi) ^ (r0 & 7)) << 3)]);
                s[0][nb] = __builtin_amdgcn_mfma_f32_16x16x32_bf16(kf, qf[0][kd], s[0][nb], 0, 0, 0);
                s[1][nb] = __builtin_amdgcn_mfma_f32_16x16x32_bf16(kf, qf[1][kd], s[1][nb], 0, 0, 0);
                s[2][nb] = __builtin_amdgcn_mfma_f32_16x16x32_bf16(kf, qf[2][kd], s[2][nb], 0, 0, 0);
            }
        }
        __builtin_amdgcn_s_setprio(0);

        // softmax per chunk (per-lane, exp2 domain, defer-max)
        unsigned pk0[3][4], pk1[3][4];
        #pragma unroll
        for (int c = 0; c < 3; ++c) {
            float mt = fmaxf(fmaxf(fmaxf(s[c][0][0], s[c][0][1]), fmaxf(s[c][0][2], s[c][0][3])),
                       fmaxf(fmaxf(fmaxf(s[c][1][0], s[c][1][1]), fmaxf(s[c][1][2], s[c][1][3])),
                       fmaxf(fmaxf(fmaxf(s[c][2][0], s[c][2][1]), fmaxf(s[c][2][2], s[c][2][3])),
                             fmaxf(fmaxf(s[c][3][0], s[c][3][1]), fmaxf(s[c][3][2], s[c][3][3])))));
            if (!__all(mt - mrun[c] <= 8.0f)) {
                float mr = fmaxf(mt, __shfl_xor(mt, 16));
                mr = fmaxf(mr, __shfl_xor(mr, 32));
                float mn = fmaxf(mrun[c], mr);
                float scl = exp2f(mrun[c] - mn);
                mrun[c] = mn;
                lrun[c] *= scl;
                #pragma unroll
                for (int db = 0; db < 8; ++db)
                    #pragma unroll
                    for (int j = 0; j < 4; ++j)
                        oacc[c][db][j] *= scl;
            }
            float rt = 0.f;
            #pragma unroll
            for (int nb = 0; nb < 4; ++nb)
                #pragma unroll
                for (int j = 0; j < 4; ++j) {
                    s[c][nb][j] = exp2f(s[c][nb][j] - mrun[c]);
                    rt += s[c][nb][j];
                }
            lrun[c] += rt;   // per-hi partial; reduced at the end
            #pragma unroll
            for (int nb = 0; nb < 4; ++nb) {
                asm("v_cvt_pk_bf16_f32 %0, %1, %2" : "=v"(pk0[c][nb]) : "v"(s[c][nb][0]), "v"(s[c][nb][1]));
                asm("v_cvt_pk_bf16_f32 %0, %1, %2" : "=v"(pk1[c][nb]) : "v"(s[c][nb][2]), "v"(s[c][nb][3]));
            }
        }

        // PV: each vf read feeds 3 MFMAs; P-fragment lane-local
        __builtin_amdgcn_s_setprio(1);
        #pragma unroll
        for (int kd = 0; kd < 2; ++kd) {
            short8 pf[3];
            #pragma unroll
            for (int c = 0; c < 3; ++c) {
                i32x4 fr;
                fr[0] = (int)pk0[c][2 * kd];
                fr[1] = (int)pk1[c][2 * kd];
                fr[2] = (int)pk0[c][2 * kd + 1];
                fr[3] = (int)pk1[c][2 * kd + 1];
                pf[c] = *reinterpret_cast<short8*>(&fr);
            }
            #pragma unroll
            for (int db = 0; db < 8; ++db) {
                short8 vf = *reinterpret_cast<const short8*>(
                    &VTb[(db * 16 + r0) * 64 + (((kd * 4 + hi) ^ (r0 & 7)) << 3)]);
                oacc[0][db] = __builtin_amdgcn_mfma_f32_16x16x32_bf16(vf, pf[0], oacc[0][db], 0, 0, 0);
                oacc[1][db] = __builtin_amdgcn_mfma_f32_16x16x32_bf16(vf, pf[1], oacc[1][db], 0, 0, 0);
                oacc[2][db] = __builtin_amdgcn_mfma_f32_16x16x32_bf16(vf, pf[2], oacc[2][db], 0, 0, 0);
            }
        }
        __builtin_amdgcn_s_setprio(0);
    }

    #pragma unroll
    for (int c = 0; c < 3; ++c) {
        float lr = lrun[c];
        lr += __shfl_xor(lr, 16);
        lr += __shfl_xor(lr, 32);
        const float inv = 1.f / lr;
        const long po = ((long)(sp * 32 + bh) * NTOK + qt * 192 + c * 64 + wid * 16 + r0) * HD;
        #pragma unroll
        for (int db = 0; db < 8; ++db) {
            ushort4 o;
            o.x = f2us(oacc[c][db][0] * inv);
            o.y = f2us(oacc[c][db][1] * inv);
            o.z = f2us(oacc[c][db][2] * inv);
            o.w = f2us(oacc[c][db][3] * inv);
            *(ushort4*)&Opart[po + db * 16 + hi * 4] = o;
        }
        if (lane < 16) {
            const long mo = (long)(sp * 32 + bh) * NTOK + qt * 192 + c * 64 + wid * 16 + r0;
            Ml[mo] = make_float2(mrun[c], lr);   // log2 domain
        }
    }
}

// Combine NSPLIT partials -> Ob[(b*576+n)*1024 + h*128 + d]
__global__ __launch_bounds__(256)
void attn_reduce(const unsigned short* __restrict__ Opart, const float2* __restrict__ Ml,
                 unsigned short* __restrict__ Ob)
{
    const int qt = blockIdx.x, bh = blockIdx.y;
    const int t = threadIdx.x;
    const int rl = t >> 2, dc = (t & 3) * 32;
    const int q = qt * 64 + rl;

    float m[NSPLIT], l[NSPLIT];
    float M = -1e30f;
    #pragma unroll
    for (int sp = 0; sp < NSPLIT; ++sp) {
        float2 v = Ml[(long)(sp * 32 + bh) * NTOK + q];
        m[sp] = v.x; l[sp] = v.y;
        M = fmaxf(M, v.x);
    }
    float w[NSPLIT], denom = 0.f;
    #pragma unroll
    for (int sp = 0; sp < NSPLIT; ++sp) {
        w[sp] = l[sp] * exp2f(m[sp] - M);
        denom += w[sp];
    }
    const float inv = 1.f / denom;
    const int b = bh >> 3, h = bh & 7;
    #pragma unroll
    for (int dj = 0; dj < 4; ++dj) {
        float a[8];
        #pragma unroll
        for (int e = 0; e < 8; ++e) a[e] = 0.f;
        #pragma unroll
        for (int sp = 0; sp < NSPLIT; ++sp) {
            short8 v = *reinterpret_cast<const short8*>(
                &Opart[((long)(sp * 32 + bh) * NTOK + q) * HD + dc + dj * 8]);
            #pragma unroll
            for (int e = 0; e < 8; ++e)
                a[e] += w[sp] * us2f((unsigned short)v[e]);
        }
        short8 o;
        #pragma unroll
        for (int e = 0; e < 8; ++e) o[e] = (short)f2us(a[e] * inv);
        *reinterpret_cast<short8*>(&Ob[((long)b * NTOK + q) * 1024 + h * 128 + dc + dj * 8]) = o;
    }
}

// LayerNorm(y)*g + b + vision; output dtype per meta[0]
__global__ __launch_bounds__(256)
void ln2_kernel(const unsigned short* __restrict__ Y, const unsigned short* __restrict__ g,
                const unsigned short* __restrict__ be, const unsigned short* __restrict__ vis,
                void* __restrict__ dout, const int* __restrict__ meta)
{
    const int row = blockIdx.x;
    const int tid = threadIdx.x;
    const int lane = tid & 63, wid = tid >> 6;
    const unsigned short* yr = Y + (long)row * DIM;
    ushort4 raw = reinterpret_cast<const ushort4*>(yr)[tid];
    float v[4];
    v[0] = us2f(raw.x); v[1] = us2f(raw.y); v[2] = us2f(raw.z); v[3] = us2f(raw.w);
    float s1 = 0.f, s2 = 0.f;
    #pragma unroll
    for (int i = 0; i < 4; ++i) { s1 += v[i]; s2 += v[i] * v[i]; }
    #pragma unroll
    for (int off = 1; off < 64; off <<= 1) {
        s1 += __shfl_xor(s1, off);
        s2 += __shfl_xor(s2, off);
    }
    __shared__ float red[2][4];
    if (lane == 0) { red[0][wid] = s1; red[1][wid] = s2; }
    __syncthreads();
    s1 = red[0][0] + red[0][1] + red[0][2] + red[0][3];
    s2 = red[1][0] + red[1][1] + red[1][2] + red[1][3];
    const float mu = s1 * (1.f / DIM);
    const float var = s2 * (1.f / DIM) - mu * mu;
    const float inv = rsqrtf(var + 1e-5f);
    ushort4 gg = reinterpret_cast<const ushort4*>(g)[tid];
    ushort4 bb = reinterpret_cast<const ushort4*>(be)[tid];
    ushort4 vv = reinterpret_cast<const ushort4*>(vis + (long)row * DIM)[tid];
    float o0 = (v[0] - mu) * inv * us2f(gg.x) + us2f(bb.x) + us2f(vv.x);
    float o1 = (v[1] - mu) * inv * us2f(gg.y) + us2f(bb.y) + us2f(vv.y);
    float o2 = (v[2] - mu) * inv * us2f(gg.z) + us2f(bb.z) + us2f(vv.z);
    float o3 = (v[3] - mu) * inv * us2f(gg.w) + us2f(bb.w) + us2f(vv.w);
    if (meta[0]) {
        ushort4 o;
        o.x = f2us(o0); o.y = f2us(o1); o.z = f2us(o2); o.w = f2us(o3);
        reinterpret_cast<ushort4*>((unsigned short*)dout + (long)row * DIM)[tid] = o;
    } else {
        float4 o = make_float4(o0, o1, o2, o3);
        reinterpret_cast<float4*>((float*)dout + (long)row * DIM)[tid] = o;
    }
}

extern "C" void kernel_launch(void* const* d_in, const int* in_sizes, int n_in,
                              void* d_out, int out_size, void* d_ws, size_t ws_size,
                              hipStream_t stream)
{
    // scan_idx (d_in[11]) unused: all 8 scans are bijections on the 576 cells and
    // softmax over the full K*N key axis (K,V share row order) is permutation-
    // invariant per direction block -> gather elided.
    unsigned long long w = (unsigned long long)d_ws;
    int* meta = (int*)w; w += 256;

    const int cidx[10] = {0, 2, 3, 4, 5, 6, 7, 8, 9, 10};
    const long csz[10] = {
        (long)NB * NTOK * DIM,  // vision
        (long)KDIR * DIM,       // dirb
        3L * DIM * DIM,         // inW
        3L * DIM,               // inB
        (long)DIM * DIM,        // outW
        DIM,                    // outB
        (long)DIM * DIM,        // finW
        DIM, DIM, DIM           // finB, lng, lnb
    };
    unsigned short* cv[10];
    for (int i = 0; i < 10; ++i) {
        cv[i] = (unsigned short*)w;
        w += (csz[i] * 2 + 255) & ~255ULL;
    }
    unsigned short* dWT = (unsigned short*)w; w += (long)KDIR * DIM * DIM * 2;

    const size_t big = (size_t)NB * KDIR * NTOK * DIM * 2;   // 37.75 MB
    const size_t sml = (size_t)NB * NTOK * DIM * 2;          // 4.72 MB
    unsigned short* dirs = (unsigned short*)w; w += big;     // aliased as Opart later
    unsigned short* Kh   = (unsigned short*)w; w += big;
    unsigned short* VTh  = (unsigned short*)w; w += big;
    unsigned short* Qh   = (unsigned short*)w; w += sml;
    unsigned short* Ob   = (unsigned short*)w; w += sml;
    unsigned short* Fu   = (unsigned short*)w; w += sml;
    unsigned short* Y2   = (unsigned short*)w; w += sml;
    float2* Ml = (float2*)w; w += (long)NSPLIT * 32 * NTOK * sizeof(float2);
    unsigned short* Opart = dirs;   // dirs dead after KV GEMM; 6*4.72=28.3MB < 37.75MB

    const unsigned short* vision = cv[0];
    const unsigned short* dirb = cv[1];
    const unsigned short* inW = cv[2];
    const unsigned short* inB = cv[3];
    const unsigned short* outW = cv[4];
    const unsigned short* outB = cv[5];
    const unsigned short* finW = cv[6];
    const unsigned short* finB = cv[7];
    const unsigned short* lng = cv[8];
    const unsigned short* lnbt = cv[9];

    dim3 blk(256, 1, 1);

    // 0. dtype detect
    detect_kernel<<<dim3(1), dim3(64), 0, stream>>>((const unsigned int*)d_in[1], meta);

    // 1. single fused conversion launch (+ transposed dirW)
    ConvJobs J;
    int bacc = 0;
    for (int i = 0; i < 10; ++i) {
        J.src[i] = d_in[cidx[i]];
        J.dst[i] = cv[i];
        J.n4[i] = (int)(csz[i] / 4);
        J.bstart[i] = bacc;
        bacc += (int)((csz[i] / 4 + 1023) / 1024);
    }
    conv_all<<<dim3(bacc), blk, 0, stream>>>(J, meta);
    transpose_conv<<<dim3(1024, KDIR), blk, 0, stream>>>(d_in[1], dWT, meta);

    // 2. merged dirs(z<8)+Q(z==8, pre-scaled) GEMM: A=vision, M=2304
    gemm_glds<6, 8, 128, 128><<<dim3(18 * 8, 9), blk, 0, stream>>>(
        vision, dWT, dirb, dirs, inW, inB, Qh, NB * NTOK, (long)DIM * DIM, DIM);

    // 3. fused K+V GEMM (wk||wv contiguous): K->Kh, V->VTh (phi-permuted)
    gemm_glds<5, 16, 128, 128><<<dim3(144 * 16, 1), blk, 0, stream>>>(
        dirs, inW + DIM * DIM, inB + DIM, Kh, nullptr, nullptr, VTh, NB * KN, 0L, 0L);

    // 4. 3-chunk KV-split flash attention -> Opart (aliases dirs) + Ml
    attn_kernel7<<<dim3(3 * 32 * NSPLIT), blk, 0, stream>>>(Qh, Kh, VTh, Opart, Ml);

    // 5. combine partials -> Ob [b,n,h*128+d]
    attn_reduce<<<dim3(9, 32), blk, 0, stream>>>(Opart, Ml, Ob);

    // 6. fused = Ob @ out_proj^T + b   (64x64 tile: 576 blocks)
    gemm_glds<0, 16, 64, 64><<<dim3(36 * 16, 1), blk, 0, stream>>>(
        Ob, outW, outB, Fu, nullptr, nullptr, nullptr, NB * NTOK, 0L, 0L);

    // 7. y = fused @ fin^T + b
    gemm_glds<0, 16, 64, 64><<<dim3(36 * 16, 1), blk, 0, stream>>>(
        Fu, finW, finB, Y2, nullptr, nullptr, nullptr, NB * NTOK, 0L, 0L);

    // 8. LayerNorm + residual -> d_out
    ln2_kernel<<<dim3(NB * NTOK), blk, 0, stream>>>(Y2, lng, lnbt, vision, d_out, meta);
}

// Round 13
// 344.697 us; speedup vs baseline: 1.0618x; 1.0001x over previous
//
#include <hip/hip_runtime.h>
#include <hip/hip_bf16.h>

typedef __attribute__((ext_vector_type(8))) short short8;
typedef __attribute__((ext_vector_type(4))) float f32x4;
typedef __attribute__((ext_vector_type(4))) int i32x4;

#define NTOK 576
#define DIM  1024
#define NB   4
#define NH   8
#define HD   128
#define KDIR 8
#define KN   4608
#define NSPLIT 4
#define NT 18                 // KN/NSPLIT/64

__device__ __forceinline__ float us2f(unsigned short u) {
    unsigned int x = ((unsigned int)u) << 16;
    return __uint_as_float(x);
}
__device__ __forceinline__ unsigned short f2us(float f) {
    unsigned int x = __float_as_uint(f);
    unsigned int r = x + 0x7fffu + ((x >> 16) & 1u);
    return (unsigned short)(r >> 16);
}

typedef __attribute__((address_space(3))) unsigned int lds_uint;
typedef const __attribute__((address_space(1))) unsigned int glb_uint;
__device__ __forceinline__ void async16(const unsigned short* g, unsigned short* l) {
    __builtin_amdgcn_global_load_lds((glb_uint*)g, (lds_uint*)l, 16, 0, 0);
}
__device__ __forceinline__ void wait_vm0_barrier() {
    asm volatile("s_waitcnt vmcnt(0)" ::: "memory");
    __builtin_amdgcn_s_barrier();
    __builtin_amdgcn_sched_barrier(0);
}

// meta[0] = 1 if device buffers are bf16, 0 if f32
__global__ void detect_kernel(const unsigned int* __restrict__ src, int* meta)
{
    if (threadIdx.x == 0) {
        int cnt = 0;
        for (int i = 0; i < 256; ++i) {
            unsigned u = src[(long)i * 16384] & 0xFFFFu;
            unsigned e = (u >> 7) & 0xFFu;
            cnt += (e >= 90 && e <= 150) ? 1 : 0;
        }
        meta[0] = (cnt >= 192) ? 1 : 0;
    }
}

// All 11 conversions (incl. dirW, native layout) in one launch.
struct ConvJobs {
    const void* src[11];
    unsigned short* dst[11];
    int n4[11];
    int bstart[11];
};
__global__ __launch_bounds__(256)
void conv_all(ConvJobs J, const int* __restrict__ meta)
{
    const int b = blockIdx.x;
    int ji = 0;
    #pragma unroll
    for (int i = 1; i < 11; ++i) if (b >= J.bstart[i]) ji = i;
    const long base = (long)(b - J.bstart[ji]) * 1024 + threadIdx.x;
    const long n4 = J.n4[ji];
    if (meta[0]) {
        const ushort4* s = (const ushort4*)J.src[ji];
        ushort4* d = (ushort4*)J.dst[ji];
        #pragma unroll
        for (int t = 0; t < 4; ++t) {
            long i = base + t * 256;
            if (i < n4) d[i] = s[i];
        }
    } else {
        const float4* s = (const float4*)J.src[ji];
        ushort4* d = (ushort4*)J.dst[ji];
        #pragma unroll
        for (int t = 0; t < 4; ++t) {
            long i = base + t * 256;
            if (i < n4) {
                float4 v = s[i];
                ushort4 o;
                o.x = f2us(v.x); o.y = f2us(v.y); o.z = f2us(v.z); o.w = f2us(v.w);
                d[i] = o;
            }
        }
    }
}

// bkv[z*2048+j] = dot(dirb[z], wkv[j]) + inbkv[j].  One wave per (z,j).
__global__ __launch_bounds__(256)
void bias_fold(const unsigned short* __restrict__ dirb, const unsigned short* __restrict__ wkv,
               const unsigned short* __restrict__ inbkv, unsigned short* __restrict__ bkv)
{
    const int w4 = threadIdx.x >> 6, lane = threadIdx.x & 63;
    const int p = blockIdx.x * 4 + w4;           // 0..16383
    const int z = p >> 11, j = p & 2047;
    const unsigned short* a = dirb + z * 1024 + lane * 16;
    const unsigned short* b = wkv + (long)j * 1024 + lane * 16;
    short8 av0 = *(const short8*)a, av1 = *(const short8*)(a + 8);
    short8 bv0 = *(const short8*)b, bv1 = *(const short8*)(b + 8);
    float s = 0.f;
    #pragma unroll
    for (int e = 0; e < 8; ++e) {
        s += us2f((unsigned short)av0[e]) * us2f((unsigned short)bv0[e]);
        s += us2f((unsigned short)av1[e]) * us2f((unsigned short)bv1[e]);
    }
    #pragma unroll
    for (int off = 1; off < 64; off <<= 1) s += __shfl_xor(s, off);
    if (lane == 0) bkv[p] = f2us(s + us2f(inbkv[j]));
}

// C = A[M x 1024] @ B^T + bias. Tile BM x BN, BK=64, single-buffer glds staging
// (m97 structure: 32KB LDS, 5 blocks/CU).
// MODE 0: row-major C + bias (out/fin projections)
// MODE 7: weight fold Fkv[z][j][d] = sum_e dirW[z][d][e]*wkv[j][e]; no bias;
//         A batched by z (aStride), B shared.
// MODE 8: KVQ. z<8: B=Fkv[z], bias=bkv[z]; K half -> Kh [bh][kv][128];
//         V half -> VTh [bh][128][4608] (kv phi-permuted per 64-block).
//         z==8 (tn<8): B=wq, bias=bq -> Qh [bh][n][d] pre-scaled.
template<int MODE, int TN, int BM, int BN>
__global__ __launch_bounds__(256)
void gemm_glds(const unsigned short* __restrict__ A, const unsigned short* __restrict__ Bw,
               const unsigned short* __restrict__ bias, unsigned short* __restrict__ C,
               const unsigned short* __restrict__ B2, const unsigned short* __restrict__ bias2,
               unsigned short* __restrict__ C2, unsigned short* __restrict__ C3,
               int M, long aStride, long bStride, long biasStride)
{
    constexpr int MI = BM / 32, NI = BN / 32;
    const int z = blockIdx.y;
    const int tm = blockIdx.x / TN;
    const int tn = blockIdx.x % TN;
    const unsigned short* Ab = A + (long)z * aStride;
    const unsigned short* Bb;
    const unsigned short* Gb;
    if constexpr (MODE == 8) {
        if (z == 8 && tn >= 8) return;
        Bb = (z < 8) ? Bw + (long)z * bStride : B2;
        Gb = (z < 8) ? bias + (long)z * biasStride : bias2;
    } else {
        Bb = Bw + (long)z * bStride;
        Gb = bias + (long)z * biasStride;
    }

    __shared__ __align__(16) unsigned short As[BM * 64];
    __shared__ __align__(16) unsigned short Bs[BN * 64];

    const int tid = threadIdx.x, lane = tid & 63, wid = tid >> 6;
    const int wm = wid >> 1, wn = wid & 1;
    const int r0 = lane & 15, hi = lane >> 4;
    const int lr = lane >> 3;
    const int lg = lane & 7;

    f32x4 zz = {0.f, 0.f, 0.f, 0.f};
    f32x4 acc[MI][NI];
    #pragma unroll
    for (int i = 0; i < MI; ++i)
        #pragma unroll
        for (int j = 0; j < NI; ++j) acc[i][j] = zz;

    const int sgc = ((lg ^ (lr & 7)) << 3);

    for (int k0 = 0; k0 < 1024; k0 += 64) {
        #pragma unroll
        for (int j = 0; j < BM / 32; ++j) {
            int rb = wid * (BM / 4) + j * 8;
            async16(Ab + (long)(tm * BM + rb + lr) * 1024 + k0 + sgc, &As[rb * 64]);
        }
        #pragma unroll
        for (int j = 0; j < BN / 32; ++j) {
            int rb = wid * (BN / 4) + j * 8;
            async16(Bb + (long)(tn * BN + rb + lr) * 1024 + k0 + sgc, &Bs[rb * 64]);
        }
        __syncthreads();
        __builtin_amdgcn_s_setprio(1);
        #pragma unroll
        for (int kd = 0; kd < 2; ++kd) {
            const int pg = ((kd * 4 + hi) ^ (r0 & 7)) << 3;
            short8 af[MI], bfr[NI];
            #pragma unroll
            for (int mi = 0; mi < MI; ++mi)
                af[mi] = *reinterpret_cast<const short8*>(&As[(wm * (BM/2) + mi * 16 + r0) * 64 + pg]);
            #pragma unroll
            for (int ni = 0; ni < NI; ++ni)
                bfr[ni] = *reinterpret_cast<const short8*>(&Bs[(wn * (BN/2) + ni * 16 + r0) * 64 + pg]);
            #pragma unroll
            for (int mi = 0; mi < MI; ++mi)
                #pragma unroll
                for (int ni = 0; ni < NI; ++ni)
                    acc[mi][ni] = __builtin_amdgcn_mfma_f32_16x16x32_bf16(af[mi], bfr[ni], acc[mi][ni], 0, 0, 0);
        }
        __builtin_amdgcn_s_setprio(0);
        __syncthreads();
    }

    const float QSCL = 0.08838834764831845f * 1.4426950408889634f;
    const int jr = hi * 4;
    #pragma unroll
    for (int ni = 0; ni < NI; ++ni) {
        int cg = tn * BN + wn * (BN/2) + ni * 16 + r0;
        if constexpr (MODE == 7) {
            // Fkv[z][j=cg][d=rg..rg+3], no bias
            #pragma unroll
            for (int mi = 0; mi < MI; ++mi) {
                int rg = tm * BM + wm * (BM/2) + mi * 16 + jr;
                ushort4 o;
                o.x = f2us(acc[mi][ni][0]);
                o.y = f2us(acc[mi][ni][1]);
                o.z = f2us(acc[mi][ni][2]);
                o.w = f2us(acc[mi][ni][3]);
                *(ushort4*)&C[((long)z * 2048 + cg) * 1024 + rg] = o;
            }
        } else if constexpr (MODE == 8) {
            float bv = us2f(Gb[cg]);
            if (z == 8) {
                int h = cg >> 7, d = cg & 127;
                #pragma unroll
                for (int mi = 0; mi < MI; ++mi) {
                    #pragma unroll
                    for (int j = 0; j < 4; ++j) {
                        int rg = tm * BM + wm * (BM/2) + mi * 16 + jr + j;
                        int b = rg / 576, n = rg - b * 576;
                        C3[((long)(b * 8 + h) * 576 + n) * 128 + d] = f2us((acc[mi][ni][j] + bv) * QSCL);
                    }
                }
            } else if (cg >= 1024) {
                int cg2 = cg - 1024;
                int h = cg2 >> 7, d = cg2 & 127;
                #pragma unroll
                for (int mi = 0; mi < MI; ++mi) {
                    int rgb = tm * BM + wm * (BM/2) + mi * 16 + jr;
                    int b = rgb / 576, n = rgb - b * 576;
                    int kv = z * 576 + n;
                    int r = kv & 63;
                    int P = ((r >> 5) & 1) * 32 + ((r >> 3) & 1) * 16 + ((r >> 2) & 1) * 8
                          + ((r >> 4) & 1) * 4 + (r & 3);
                    ushort4 o;
                    o.x = f2us(acc[mi][ni][0] + bv);
                    o.y = f2us(acc[mi][ni][1] + bv);
                    o.z = f2us(acc[mi][ni][2] + bv);
                    o.w = f2us(acc[mi][ni][3] + bv);
                    *(ushort4*)&C2[((long)(b * 8 + h) * 128 + d) * 4608 + (kv & ~63) + P] = o;
                }
            } else {
                int h = cg >> 7, d = cg & 127;
                #pragma unroll
                for (int mi = 0; mi < MI; ++mi) {
                    #pragma unroll
                    for (int j = 0; j < 4; ++j) {
                        int rg = tm * BM + wm * (BM/2) + mi * 16 + jr + j;
                        int b = rg / 576, n = rg - b * 576;
                        int kv = z * 576 + n;
                        C[((long)(b * 8 + h) * 4608 + kv) * 128 + d] = f2us(acc[mi][ni][j] + bv);
                    }
                }
            }
        } else {
            float bv = us2f(Gb[cg]);
            #pragma unroll
            for (int mi = 0; mi < MI; ++mi) {
                #pragma unroll
                for (int j = 0; j < 4; ++j) {
                    int rg = tm * BM + wm * (BM/2) + mi * 16 + jr + j;
                    C[(long)rg * 1024 + cg] = f2us(acc[mi][ni][j] + bv);
                }
            }
        }
    }
}

// 3-chunk swapped-operand flash attention (round-10 proven version, NSPLIT=4).
__global__ __launch_bounds__(256, 2)
void attn_kernel7(const unsigned short* __restrict__ Qh, const unsigned short* __restrict__ Kh,
                  const unsigned short* __restrict__ VTh, unsigned short* __restrict__ Opart,
                  float2* __restrict__ Ml)
{
    const int bid = blockIdx.x;
    const int logical = (bid & 7) * 48 + (bid >> 3);   // 384 blocks, XCD-grouped
    const int bhsp = logical / 3;
    const int qt = logical - bhsp * 3;
    const int bh = bhsp >> 2;
    const int sp = bhsp & 3;

    const int tid = threadIdx.x;
    const int lane = tid & 63, wid = tid >> 6;
    const int r0 = lane & 15, hi = lane >> 4;

    __shared__ __align__(16) unsigned short Ks[2][64 * 128];
    __shared__ __align__(16) unsigned short VT[2][128 * 64];

    short8 qf[3][4];
    #pragma unroll
    for (int c = 0; c < 3; ++c) {
        const long qoff = ((long)bh * NTOK + qt * 192 + c * 64 + wid * 16 + r0) * HD + hi * 8;
        #pragma unroll
        for (int kd = 0; kd < 4; ++kd)
            qf[c][kd] = *reinterpret_cast<const short8*>(Qh + qoff + kd * 32);
    }

    f32x4 zz = {0.f, 0.f, 0.f, 0.f};
    f32x4 oacc[3][8];
    #pragma unroll
    for (int c = 0; c < 3; ++c)
        #pragma unroll
        for (int i = 0; i < 8; ++i) oacc[c][i] = zz;
    float mrun[3], lrun[3];
    #pragma unroll
    for (int c = 0; c < 3; ++c) { mrun[c] = -1e30f; lrun[c] = 0.f; }

    int offK[4], offV[4];
    #pragma unroll
    for (int j = 0; j < 4; ++j) {
        offK[j] = (wid * 16 + 4 * j + hi) * 128 + (((lane & 15) ^ ((4 * j + hi) & 7)) << 3);
        offV[j] = (wid * 32 + 8 * j + (lane >> 3)) * KN + (((lane & 7) ^ (lane >> 3)) << 3);
    }
    const unsigned short* kp = Kh + (long)bh * KN * HD + (long)(sp * (KN / NSPLIT)) * HD;
    const unsigned short* vp = VTh + (long)bh * HD * KN + sp * (KN / NSPLIT);

    auto stage = [&](int buf) {
        #pragma unroll
        for (int j = 0; j < 4; ++j) {
            async16(kp + offK[j], &Ks[buf][(wid * 16 + 4 * j) * 128]);
            async16(vp + offV[j], &VT[buf][(wid * 32 + 8 * j) * 64]);
        }
    };

    stage(0);
    for (int kt = 0; kt < NT; ++kt) {
        wait_vm0_barrier();
        if (kt < NT - 1) { kp += 64 * HD; vp += 64; stage((kt + 1) & 1); }
        const unsigned short* Ksb = Ks[kt & 1];
        const unsigned short* VTb = VT[kt & 1];

        f32x4 s[3][4];
        #pragma unroll
        for (int c = 0; c < 3; ++c)
            #pragma unroll
            for (int nb = 0; nb < 4; ++nb) s[c][nb] = zz;
        __builtin_amdgcn_s_setprio(1);
        #pragma unroll
        for (int nb = 0; nb < 4; ++nb) {
            #pragma unroll
            for (int kd = 0; kd < 4; ++kd) {
                short8 kf = *reinterpret_cast<const short8*>(
                    &Ksb[(nb * 16 + r0) * 128 + (((kd * 4 + hi) ^ (r0 & 7)) << 3)]);
                s[0][nb] = __builtin_amdgcn_mfma_f32_16x16x32_bf16(kf, qf[0][kd], s[0][nb], 0, 0, 0);
                s[1][nb] = __builtin_amdgcn_mfma_f32_16x16x32_bf16(kf, qf[1][kd], s[1][nb], 0, 0, 0);
                s[2][nb] = __builtin_amdgcn_mfma_f32_16x16x32_bf16(kf, qf[2][kd], s[2][nb], 0, 0, 0);
            }
        }
        __builtin_amdgcn_s_setprio(0);

        unsigned pk0[3][4], pk1[3][4];
        #pragma unroll
        for (int c = 0; c < 3; ++c) {
            float mt = fmaxf(fmaxf(fmaxf(s[c][0][0], s[c][0][1]), fmaxf(s[c][0][2], s[c][0][3])),
                       fmaxf(fmaxf(fmaxf(s[c][1][0], s[c][1][1]), fmaxf(s[c][1][2], s[c][1][3])),
                       fmaxf(fmaxf(fmaxf(s[c][2][0], s[c][2][1]), fmaxf(s[c][2][2], s[c][2][3])),
                             fmaxf(fmaxf(s[c][3][0], s[c][3][1]), fmaxf(s[c][3][2], s[c][3][3])))));
            if (!__all(mt - mrun[c] <= 8.0f)) {
                float mr = fmaxf(mt, __shfl_xor(mt, 16));
                mr = fmaxf(mr, __shfl_xor(mr, 32));
                float mn = fmaxf(mrun[c], mr);
                float scl = exp2f(mrun[c] - mn);
                mrun[c] = mn;
                lrun[c] *= scl;
                #pragma unroll
                for (int db = 0; db < 8; ++db)
                    #pragma unroll
                    for (int j = 0; j < 4; ++j)
                        oacc[c][db][j] *= scl;
            }
            float rt = 0.f;
            #pragma unroll
            for (int nb = 0; nb < 4; ++nb)
                #pragma unroll
                for (int j = 0; j < 4; ++j) {
                    s[c][nb][j] = exp2f(s[c][nb][j] - mrun[c]);
                    rt += s[c][nb][j];
                }
            lrun[c] += rt;
            #pragma unroll
            for (int nb = 0; nb < 4; ++nb) {
                asm("v_cvt_pk_bf16_f32 %0, %1, %2" : "=v"(pk0[c][nb]) : "v"(s[c][nb][0]), "v"(s[c][nb][1]));
                asm("v_cvt_pk_bf16_f32 %0, %1, %2" : "=v"(pk1[c][nb]) : "v"(s[c][nb][2]), "v"(s[c][nb][3]));
            }
        }

        __builtin_amdgcn_s_setprio(1);
        #pragma unroll
        for (int kd = 0; kd < 2; ++kd) {
            short8 pf[3];
            #pragma unroll
            for (int c = 0; c < 3; ++c) {
                i32x4 fr;
                fr[0] = (int)pk0[c][2 * kd];
                fr[1] = (int)pk1[c][2 * kd];
                fr[2] = (int)pk0[c][2 * kd + 1];
                fr[3] = (int)pk1[c][2 * kd + 1];
                pf[c] = *reinterpret_cast<short8*>(&fr);
            }
            #pragma unroll
            for (int db = 0; db < 8; ++db) {
                short8 vf = *reinterpret_cast<const short8*>(
                    &VTb[(db * 16 + r0) * 64 + (((kd * 4 + hi) ^ (r0 & 7)) << 3)]);
                oacc[0][db] = __builtin_amdgcn_mfma_f32_16x16x32_bf16(vf, pf[0], oacc[0][db], 0, 0, 0);
                oacc[1][db] = __builtin_amdgcn_mfma_f32_16x16x32_bf16(vf, pf[1], oacc[1][db], 0, 0, 0);
                oacc[2][db] = __builtin_amdgcn_mfma_f32_16x16x32_bf16(vf, pf[2], oacc[2][db], 0, 0, 0);
            }
        }
        __builtin_amdgcn_s_setprio(0);
    }

    #pragma unroll
    for (int c = 0; c < 3; ++c) {
        float lr = lrun[c];
        lr += __shfl_xor(lr, 16);
        lr += __shfl_xor(lr, 32);
        const float inv = 1.f / lr;
        const long po = ((long)(sp * 32 + bh) * NTOK + qt * 192 + c * 64 + wid * 16 + r0) * HD;
        #pragma unroll
        for (int db = 0; db < 8; ++db) {
            ushort4 o;
            o.x = f2us(oacc[c][db][0] * inv);
            o.y = f2us(oacc[c][db][1] * inv);
            o.z = f2us(oacc[c][db][2] * inv);
            o.w = f2us(oacc[c][db][3] * inv);
            *(ushort4*)&Opart[po + db * 16 + hi * 4] = o;
        }
        if (lane < 16) {
            const long mo = (long)(sp * 32 + bh) * NTOK + qt * 192 + c * 64 + wid * 16 + r0;
            Ml[mo] = make_float2(mrun[c], lr);
        }
    }
}

// Combine NSPLIT partials -> Ob[(b*576+n)*1024 + h*128 + d]
__global__ __launch_bounds__(256)
void attn_reduce(const unsigned short* __restrict__ Opart, const float2* __restrict__ Ml,
                 unsigned short* __restrict__ Ob)
{
    const int qt = blockIdx.x, bh = blockIdx.y;
    const int t = threadIdx.x;
    const int rl = t >> 2, dc = (t & 3) * 32;
    const int q = qt * 64 + rl;

    float m[NSPLIT], l[NSPLIT];
    float M = -1e30f;
    #pragma unroll
    for (int sp = 0; sp < NSPLIT; ++sp) {
        float2 v = Ml[(long)(sp * 32 + bh) * NTOK + q];
        m[sp] = v.x; l[sp] = v.y;
        M = fmaxf(M, v.x);
    }
    float w[NSPLIT], denom = 0.f;
    #pragma unroll
    for (int sp = 0; sp < NSPLIT; ++sp) {
        w[sp] = l[sp] * exp2f(m[sp] - M);
        denom += w[sp];
    }
    const float inv = 1.f / denom;
    const int b = bh >> 3, h = bh & 7;
    #pragma unroll
    for (int dj = 0; dj < 4; ++dj) {
        float a[8];
        #pragma unroll
        for (int e = 0; e < 8; ++e) a[e] = 0.f;
        #pragma unroll
        for (int sp = 0; sp < NSPLIT; ++sp) {
            short8 v = *reinterpret_cast<const short8*>(
                &Opart[((long)(sp * 32 + bh) * NTOK + q) * HD + dc + dj * 8]);
            #pragma unroll
            for (int e = 0; e < 8; ++e)
                a[e] += w[sp] * us2f((unsigned short)v[e]);
        }
        short8 o;
        #pragma unroll
        for (int e = 0; e < 8; ++e) o[e] = (short)f2us(a[e] * inv);
        *reinterpret_cast<short8*>(&Ob[((long)b * NTOK + q) * 1024 + h * 128 + dc + dj * 8]) = o;
    }
}

// LayerNorm(y)*g + b + vision; output dtype per meta[0]
__global__ __launch_bounds__(256)
void ln2_kernel(const unsigned short* __restrict__ Y, const unsigned short* __restrict__ g,
                const unsigned short* __restrict__ be, const unsigned short* __restrict__ vis,
                void* __restrict__ dout, const int* __restrict__ meta)
{
    const int row = blockIdx.x;
    const int tid = threadIdx.x;
    const int lane = tid & 63, wid = tid >> 6;
    const unsigned short* yr = Y + (long)row * DIM;
    ushort4 raw = reinterpret_cast<const ushort4*>(yr)[tid];
    float v[4];
    v[0] = us2f(raw.x); v[1] = us2f(raw.y); v[2] = us2f(raw.z); v[3] = us2f(raw.w);
    float s1 = 0.f, s2 = 0.f;
    #pragma unroll
    for (int i = 0; i < 4; ++i) { s1 += v[i]; s2 += v[i] * v[i]; }
    #pragma unroll
    for (int off = 1; off < 64; off <<= 1) {
        s1 += __shfl_xor(s1, off);
        s2 += __shfl_xor(s2, off);
    }
    __shared__ float red[2][4];
    if (lane == 0) { red[0][wid] = s1; red[1][wid] = s2; }
    __syncthreads();
    s1 = red[0][0] + red[0][1] + red[0][2] + red[0][3];
    s2 = red[1][0] + red[1][1] + red[1][2] + red[1][3];
    const float mu = s1 * (1.f / DIM);
    const float var = s2 * (1.f / DIM) - mu * mu;
    const float inv = rsqrtf(var + 1e-5f);
    ushort4 gg = reinterpret_cast<const ushort4*>(g)[tid];
    ushort4 bb = reinterpret_cast<const ushort4*>(be)[tid];
    ushort4 vv = reinterpret_cast<const ushort4*>(vis + (long)row * DIM)[tid];
    float o0 = (v[0] - mu) * inv * us2f(gg.x) + us2f(bb.x) + us2f(vv.x);
    float o1 = (v[1] - mu) * inv * us2f(gg.y) + us2f(bb.y) + us2f(vv.y);
    float o2 = (v[2] - mu) * inv * us2f(gg.z) + us2f(bb.z) + us2f(vv.z);
    float o3 = (v[3] - mu) * inv * us2f(gg.w) + us2f(bb.w) + us2f(vv.w);
    if (meta[0]) {
        ushort4 o;
        o.x = f2us(o0); o.y = f2us(o1); o.z = f2us(o2); o.w = f2us(o3);
        reinterpret_cast<ushort4*>((unsigned short*)dout + (long)row * DIM)[tid] = o;
    } else {
        float4 o = make_float4(o0, o1, o2, o3);
        reinterpret_cast<float4*>((float*)dout + (long)row * DIM)[tid] = o;
    }
}

extern "C" void kernel_launch(void* const* d_in, const int* in_sizes, int n_in,
                              void* d_out, int out_size, void* d_ws, size_t ws_size,
                              hipStream_t stream)
{
    // scan_idx (d_in[11]) unused: all 8 scans are bijections on the 576 cells and
    // softmax over the full K*N key axis (K,V share row order) is permutation-
    // invariant per direction block -> gather elided.
    // dirs GEMM eliminated by weight folding: K/V = vision @ (dirW[z] @ wkv^T) + fold(bias).
    unsigned long long w = (unsigned long long)d_ws;
    int* meta = (int*)w; w += 256;

    const int cidx[11] = {0, 2, 3, 4, 5, 6, 7, 8, 9, 10, 1};
    const long csz[11] = {
        (long)NB * NTOK * DIM,      // vision
        (long)KDIR * DIM,           // dirb
        3L * DIM * DIM,             // inW
        3L * DIM,                   // inB
        (long)DIM * DIM,            // outW
        DIM,                        // outB
        (long)DIM * DIM,            // finW
        DIM, DIM, DIM,              // finB, lng, lnb
        (long)KDIR * DIM * DIM      // dirW (native layout)
    };
    unsigned short* cv[11];
    for (int i = 0; i < 11; ++i) {
        cv[i] = (unsigned short*)w;
        w += (csz[i] * 2 + 255) & ~255ULL;
    }
    unsigned short* dirWb = cv[10];

    const size_t big = (size_t)NB * KDIR * NTOK * DIM * 2;       // 37.75 MB
    const size_t sml = (size_t)NB * NTOK * DIM * 2;              // 4.72 MB
    unsigned short* Fkv = (unsigned short*)w; w += (long)KDIR * 2048 * 1024 * 2;  // 32MB; aliased as Opart
    unsigned short* Kh   = (unsigned short*)w; w += big;
    unsigned short* VTh  = (unsigned short*)w; w += big;
    unsigned short* Qh   = (unsigned short*)w; w += sml;
    unsigned short* Ob   = (unsigned short*)w; w += sml;
    unsigned short* Fu   = (unsigned short*)w; w += sml;
    unsigned short* Y2   = (unsigned short*)w; w += sml;
    float2* Ml = (float2*)w; w += (long)NSPLIT * 32 * NTOK * sizeof(float2);
    unsigned short* bkv = (unsigned short*)w; w += KDIR * 2048 * 2 + 256;
    unsigned short* Opart = Fkv;   // Fkv dead after KVQ GEMM; 4*4.72=18.9MB < 32MB

    const unsigned short* vision = cv[0];
    const unsigned short* dirb = cv[1];
    const unsigned short* inW = cv[2];
    const unsigned short* inB = cv[3];
    const unsigned short* outW = cv[4];
    const unsigned short* outB = cv[5];
    const unsigned short* finW = cv[6];
    const unsigned short* finB = cv[7];
    const unsigned short* lng = cv[8];
    const unsigned short* lnbt = cv[9];

    dim3 blk(256, 1, 1);

    // 0. dtype detect
    detect_kernel<<<dim3(1), dim3(64), 0, stream>>>((const unsigned int*)d_in[1], meta);

    // 1. single fused conversion launch (now includes dirW, native layout)
    ConvJobs J;
    int bacc = 0;
    for (int i = 0; i < 11; ++i) {
        J.src[i] = d_in[cidx[i]];
        J.dst[i] = cv[i];
        J.n4[i] = (int)(csz[i] / 4);
        J.bstart[i] = bacc;
        bacc += (int)((csz[i] / 4 + 1023) / 1024);
    }
    conv_all<<<dim3(bacc), blk, 0, stream>>>(J, meta);

    // 2. weight fold: Fkv[z][j][d] = dirW[z] @ wkv^T   (17.2 GF)
    gemm_glds<7, 16, 128, 128><<<dim3(8 * 16, 8), blk, 0, stream>>>(
        dirWb, inW + DIM * DIM, nullptr, Fkv, nullptr, nullptr, nullptr, nullptr,
        1024, (long)DIM * DIM, 0L, 0L);

    // 3. bias fold: bkv[z][j] = dirb[z] . wkv[j] + inbkv[j]
    bias_fold<<<dim3(4096), blk, 0, stream>>>(dirb, inW + DIM * DIM, inB + DIM, bkv);

    // 4. KVQ GEMM: z<8 -> K/V via Fkv; z==8 -> Q via wq (tn<8)
    gemm_glds<8, 16, 128, 128><<<dim3(18 * 16, 9), blk, 0, stream>>>(
        vision, Fkv, bkv, Kh, inW, inB, VTh, Qh,
        NB * NTOK, 0L, (long)2048 * 1024, 2048L);

    // 5. 3-chunk KV-split flash attention -> Opart (aliases Fkv) + Ml
    attn_kernel7<<<dim3(3 * 32 * NSPLIT), blk, 0, stream>>>(Qh, Kh, VTh, Opart, Ml);

    // 6. combine partials -> Ob [b,n,h*128+d]
    attn_reduce<<<dim3(9, 32), blk, 0, stream>>>(Opart, Ml, Ob);

    // 7. fused = Ob @ out_proj^T + b   (64x64 tile: 576 blocks)
    gemm_glds<0, 16, 64, 64><<<dim3(36 * 16, 1), blk, 0, stream>>>(
        Ob, outW, outB, Fu, nullptr, nullptr, nullptr, nullptr, NB * NTOK, 0L, 0L, 0L);

    // 8. y = fused @ fin^T + b
    gemm_glds<0, 16, 64, 64><<<dim3(36 * 16, 1), blk, 0, stream>>>(
        Fu, finW, finB, Y2, nullptr, nullptr, nullptr, nullptr, NB * NTOK, 0L, 0L, 0L);

    // 9. LayerNorm + residual -> d_out
    ln2_kernel<<<dim3(NB * NTOK), blk, 0, stream>>>(Y2, lng, lnbt, vision, d_out, meta);
}

// Round 14
// 344.101 us; speedup vs baseline: 1.0636x; 1.0017x over previous
//
#include <hip/hip_runtime.h>
#include <hip/hip_bf16.h>

typedef __attribute__((ext_vector_type(8))) short short8;
typedef __attribute__((ext_vector_type(4))) float f32x4;
typedef __attribute__((ext_vector_type(4))) int i32x4;

#define NTOK 576
#define DIM  1024
#define NB   4
#define NH   8
#define HD   128
#define KDIR 8
#define KN   4608
#define NSPLIT 4
#define NT 18                 // KN/NSPLIT/64

__device__ __forceinline__ float us2f(unsigned short u) {
    unsigned int x = ((unsigned int)u) << 16;
    return __uint_as_float(x);
}
__device__ __forceinline__ unsigned short f2us(float f) {
    unsigned int x = __float_as_uint(f);
    unsigned int r = x + 0x7fffu + ((x >> 16) & 1u);
    return (unsigned short)(r >> 16);
}

typedef __attribute__((address_space(3))) unsigned int lds_uint;
typedef const __attribute__((address_space(1))) unsigned int glb_uint;
__device__ __forceinline__ void async16(const unsigned short* g, unsigned short* l) {
    __builtin_amdgcn_global_load_lds((glb_uint*)g, (lds_uint*)l, 16, 0, 0);
}
__device__ __forceinline__ void wait_vm0_barrier() {
    asm volatile("s_waitcnt vmcnt(0)" ::: "memory");
    __builtin_amdgcn_s_barrier();
    __builtin_amdgcn_sched_barrier(0);
}

// meta[0] = 1 if device buffers are bf16, 0 if f32
__global__ void detect_kernel(const unsigned int* __restrict__ src, int* meta)
{
    if (threadIdx.x == 0) {
        int cnt = 0;
        for (int i = 0; i < 256; ++i) {
            unsigned u = src[(long)i * 16384] & 0xFFFFu;
            unsigned e = (u >> 7) & 0xFFu;
            cnt += (e >= 90 && e <= 150) ? 1 : 0;
        }
        meta[0] = (cnt >= 192) ? 1 : 0;
    }
}

// All 10 small conversions in one launch.
struct ConvJobs {
    const void* src[10];
    unsigned short* dst[10];
    int n4[10];
    int bstart[10];
};
__global__ __launch_bounds__(256)
void conv_all(ConvJobs J, const int* __restrict__ meta)
{
    const int b = blockIdx.x;
    int ji = 0;
    #pragma unroll
    for (int i = 1; i < 10; ++i) if (b >= J.bstart[i]) ji = i;
    const long base = (long)(b - J.bstart[ji]) * 1024 + threadIdx.x;
    const long n4 = J.n4[ji];
    if (meta[0]) {
        const ushort4* s = (const ushort4*)J.src[ji];
        ushort4* d = (ushort4*)J.dst[ji];
        #pragma unroll
        for (int t = 0; t < 4; ++t) {
            long i = base + t * 256;
            if (i < n4) d[i] = s[i];
        }
    } else {
        const float4* s = (const float4*)J.src[ji];
        ushort4* d = (ushort4*)J.dst[ji];
        #pragma unroll
        for (int t = 0; t < 4; ++t) {
            long i = base + t * 256;
            if (i < n4) {
                float4 v = s[i];
                ushort4 o;
                o.x = f2us(v.x); o.y = f2us(v.y); o.z = f2us(v.z); o.w = f2us(v.w);
                d[i] = o;
            }
        }
    }
}

// dirW [8][1024 d][1024 e] -> dWT [8][1024 e][1024 d]
__global__ __launch_bounds__(256)
void transpose_conv(const void* __restrict__ src, unsigned short* __restrict__ dst,
                    const int* __restrict__ meta)
{
    const int k = blockIdx.y;
    const int ty = blockIdx.x >> 5, tx = blockIdx.x & 31;
    const int d0 = ty * 32, e0 = tx * 32;
    __shared__ float tl[32][33];
    const int t = threadIdx.x;
    const int row = t >> 3, c4 = (t & 7) * 4;
    const long sbase = ((long)k * 1024 + d0 + row) * 1024 + e0 + c4;
    if (meta[0]) {
        const unsigned short* s = (const unsigned short*)src;
        ushort4 v = *(const ushort4*)(s + sbase);
        tl[row][c4+0] = us2f(v.x); tl[row][c4+1] = us2f(v.y);
        tl[row][c4+2] = us2f(v.z); tl[row][c4+3] = us2f(v.w);
    } else {
        const float* s = (const float*)src;
        float4 v = *(const float4*)(s + sbase);
        tl[row][c4+0] = v.x; tl[row][c4+1] = v.y;
        tl[row][c4+2] = v.z; tl[row][c4+3] = v.w;
    }
    __syncthreads();
    ushort4 o;
    o.x = f2us(tl[c4+0][row]); o.y = f2us(tl[c4+1][row]);
    o.z = f2us(tl[c4+2][row]); o.w = f2us(tl[c4+3][row]);
    *(ushort4*)(dst + ((long)k * 1024 + e0 + row) * 1024 + d0 + c4) = o;
}

// 128x128 single-buffer m97-structure GEMM (dirs+Q and out/fin).
// MODE 0: row-major C; MODE 6: merged dirs(z<8)+Q(z==8, pre-scaled)
template<int MODE, int TN, int BM, int BN>
__global__ __launch_bounds__(256)
void gemm_glds(const unsigned short* __restrict__ A, const unsigned short* __restrict__ Bw,
               const unsigned short* __restrict__ bias, unsigned short* __restrict__ C,
               const unsigned short* __restrict__ B2, const unsigned short* __restrict__ bias2,
               unsigned short* __restrict__ C2,
               int M, long bStride, long biasStride)
{
    constexpr int MI = BM / 32, NI = BN / 32;
    const int z = blockIdx.y;
    const unsigned short* Bb;
    const unsigned short* Gb;
    if constexpr (MODE == 6) {
        Bb = (z < 8) ? Bw + (long)z * bStride : B2;
        Gb = (z < 8) ? bias + (long)z * biasStride : bias2;
    } else {
        Bb = Bw + (long)z * bStride;
        Gb = bias + (long)z * biasStride;
    }
    const int tm = blockIdx.x / TN;
    const int tn = blockIdx.x % TN;

    __shared__ __align__(16) unsigned short As[BM * 64];
    __shared__ __align__(16) unsigned short Bs[BN * 64];

    const int tid = threadIdx.x, lane = tid & 63, wid = tid >> 6;
    const int wm = wid >> 1, wn = wid & 1;
    const int r0 = lane & 15, hi = lane >> 4;
    const int lr = lane >> 3;
    const int lg = lane & 7;

    f32x4 zz = {0.f, 0.f, 0.f, 0.f};
    f32x4 acc[MI][NI];
    #pragma unroll
    for (int i = 0; i < MI; ++i)
        #pragma unroll
        for (int j = 0; j < NI; ++j) acc[i][j] = zz;

    const int sgc = ((lg ^ (lr & 7)) << 3);

    for (int k0 = 0; k0 < 1024; k0 += 64) {
        #pragma unroll
        for (int j = 0; j < BM / 32; ++j) {
            int rb = wid * (BM / 4) + j * 8;
            async16(A + (long)(tm * BM + rb + lr) * 1024 + k0 + sgc, &As[rb * 64]);
        }
        #pragma unroll
        for (int j = 0; j < BN / 32; ++j) {
            int rb = wid * (BN / 4) + j * 8;
            async16(Bb + (long)(tn * BN + rb + lr) * 1024 + k0 + sgc, &Bs[rb * 64]);
        }
        __syncthreads();
        __builtin_amdgcn_s_setprio(1);
        #pragma unroll
        for (int kd = 0; kd < 2; ++kd) {
            const int pg = ((kd * 4 + hi) ^ (r0 & 7)) << 3;
            short8 af[MI], bfr[NI];
            #pragma unroll
            for (int mi = 0; mi < MI; ++mi)
                af[mi] = *reinterpret_cast<const short8*>(&As[(wm * (BM/2) + mi * 16 + r0) * 64 + pg]);
            #pragma unroll
            for (int ni = 0; ni < NI; ++ni)
                bfr[ni] = *reinterpret_cast<const short8*>(&Bs[(wn * (BN/2) + ni * 16 + r0) * 64 + pg]);
            #pragma unroll
            for (int mi = 0; mi < MI; ++mi)
                #pragma unroll
                for (int ni = 0; ni < NI; ++ni)
                    acc[mi][ni] = __builtin_amdgcn_mfma_f32_16x16x32_bf16(af[mi], bfr[ni], acc[mi][ni], 0, 0, 0);
        }
        __builtin_amdgcn_s_setprio(0);
        __syncthreads();
    }

    const float QSCL = 0.08838834764831845f * 1.4426950408889634f;
    const int jr = hi * 4;
    #pragma unroll
    for (int ni = 0; ni < NI; ++ni) {
        int cg = tn * BN + wn * (BN/2) + ni * 16 + r0;
        float bv = us2f(Gb[cg]);
        #pragma unroll
        for (int mi = 0; mi < MI; ++mi) {
            #pragma unroll
            for (int j = 0; j < 4; ++j) {
                int rg = tm * BM + wm * (BM/2) + mi * 16 + jr + j;
                float val = acc[mi][ni][j] + bv;
                if constexpr (MODE == 0) {
                    C[(long)rg * 1024 + cg] = f2us(val);
                } else {  // MODE 6
                    int b = rg / 576, n = rg - b * 576;
                    if (z == 8) {
                        int h = cg >> 7, d = cg & 127;
                        C2[((long)(b * 8 + h) * 576 + n) * 128 + d] = f2us(val * QSCL);
                    } else {
                        C[((long)b * 4608 + (long)z * 576 + n) * 1024 + cg] = f2us(val);
                    }
                }
            }
        }
    }
}

// 256x256 8-phase ring-staged KV GEMM (T3+T4 template, faithful port).
// 8 half-slots (128x64 each, 128 KB LDS). Per phase: {ds-read subtile || stage one
// half-tile -> barrier -> lgkmcnt(0) -> 16 MFMA -> barrier}; counted vmcnt(4) at
// phases 3 and 7 only. Stage schedule (iter j computes kt 2j,2j+1):
//   ph0: A(2j+1) h0,h1 -> H6,H7   (read this iter ph4-7; lands by ph3 wait)
//   ph1: B(2j+2) h0 -> H0   ph2: B(2j+2) h1 -> H1
//   ph4: A(2j+2) h0 -> H2   ph5: A(2j+2) h1 -> H3
//   ph6: B(2j+3) h0 -> H4   ph7: B(2j+3) h1 -> H5
// Every stage targets a half whose last read completed before a barrier preceding
// the issue (no DMA/read race); vmcnt(4) ledger verified for prologue/steady/drain.
__global__ __launch_bounds__(512, 1)
void gemm_kv8p(const unsigned short* __restrict__ A, const unsigned short* __restrict__ Bw,
               const unsigned short* __restrict__ bias, unsigned short* __restrict__ Kh,
               unsigned short* __restrict__ VTh)
{
    const int tm = blockIdx.x >> 3;      // 0..71
    const int tn = blockIdx.x & 7;       // 0..7
    __shared__ __align__(16) unsigned short Hs[8 * 8192];

    const int tid = threadIdx.x, lane = tid & 63, wid = tid >> 6;
    const int wm = wid >> 2, wn = wid & 3;
    const int r0 = lane & 15, hi = lane >> 4;

    const int srow0 = tid >> 3;                       // 0..63
    const int sg = tid & 7;
    const int dst0 = srow0 * 64 + sg * 8;             // linear dest (r=0); r=1: +4096
    const int sc0 = ((sg ^ (srow0 & 7)) << 3);        // pre-swizzled source group

    auto stageHalf = [&](int slot, const unsigned short* src) {
        async16(src + (long)srow0 * 1024 + sc0, &Hs[slot * 8192 + dst0]);
        async16(src + (long)(srow0 + 64) * 1024 + sc0, &Hs[slot * 8192 + dst0 + 4096]);
    };

    const unsigned short* Abase = A + (long)(tm * 256) * 1024;
    const unsigned short* Bbase = Bw + (long)(tn * 256) * 1024;

    // prologue: kt0 full (B h0,h1 -> H0,H1; A h0,h1 -> H2,H3), kt1 B -> H4,H5
    stageHalf(0, Bbase);
    stageHalf(1, Bbase + 131072);
    stageHalf(2, Abase);
    stageHalf(3, Abase + 131072);
    stageHalf(4, Bbase + 64);
    stageHalf(5, Bbase + 131072 + 64);
    asm volatile("s_waitcnt vmcnt(0)" ::: "memory");
    __builtin_amdgcn_s_barrier();

    f32x4 zz = {0.f, 0.f, 0.f, 0.f};
    f32x4 acc[8][4];
    #pragma unroll
    for (int i = 0; i < 8; ++i)
        #pragma unroll
        for (int j = 0; j < 4; ++j) acc[i][j] = zz;

    const int pg0 = ((hi) ^ (r0 & 7)) << 3;
    const int pg1 = ((4 + hi) ^ (r0 & 7)) << 3;

    for (int j = 0; j < 8; ++j) {
        const unsigned short* Ao  = Abase + (2 * j + 1) * 64;
        const unsigned short* An  = Abase + (2 * j + 2) * 64;
        const unsigned short* Bn  = Bbase + (2 * j + 2) * 64;
        const unsigned short* Bo2 = Bbase + (2 * j + 3) * 64;
        #pragma unroll
        for (int kt2 = 0; kt2 < 2; ++kt2) {
            const int sb = kt2 * 4;
            short8 bf[4][2];
            #pragma unroll
            for (int q = 0; q < 4; ++q) {
                if (q == 0) {
                    #pragma unroll
                    for (int ni = 0; ni < 4; ++ni) {
                        const unsigned short* bsl =
                            &Hs[(sb + (wn >> 1)) * 8192 + ((wn & 1) * 64 + ni * 16 + r0) * 64];
                        bf[ni][0] = *(const short8*)(bsl + pg0);
                        bf[ni][1] = *(const short8*)(bsl + pg1);
                    }
                }
                short8 af[2][2];
                #pragma unroll
                for (int dm = 0; dm < 2; ++dm) {
                    const unsigned short* asl =
                        &Hs[(sb + 2 + wm) * 8192 + ((2 * q + dm) * 16 + r0) * 64];
                    af[dm][0] = *(const short8*)(asl + pg0);
                    af[dm][1] = *(const short8*)(asl + pg1);
                }
                const int ph = kt2 * 4 + q;
                if (ph == 0) { stageHalf(6, Ao); stageHalf(7, Ao + 131072); }
                else if (j < 7) {
                    if (ph == 1) stageHalf(0, Bn);
                    else if (ph == 2) stageHalf(1, Bn + 131072);
                    else if (ph == 4) stageHalf(2, An);
                    else if (ph == 5) stageHalf(3, An + 131072);
                    else if (ph == 6) stageHalf(4, Bo2);
                    else if (ph == 7) stageHalf(5, Bo2 + 131072);
                }
                __builtin_amdgcn_sched_barrier(0);
                __builtin_amdgcn_s_barrier();
                asm volatile("s_waitcnt lgkmcnt(0)" ::: "memory");
                __builtin_amdgcn_sched_barrier(0);
                __builtin_amdgcn_s_setprio(1);
                #pragma unroll
                for (int dm = 0; dm < 2; ++dm)
                    #pragma unroll
                    for (int ni = 0; ni < 4; ++ni) {
                        acc[2*q+dm][ni] = __builtin_amdgcn_mfma_f32_16x16x32_bf16(af[dm][0], bf[ni][0], acc[2*q+dm][ni], 0, 0, 0);
                        acc[2*q+dm][ni] = __builtin_amdgcn_mfma_f32_16x16x32_bf16(af[dm][1], bf[ni][1], acc[2*q+dm][ni], 0, 0, 0);
                    }
                __builtin_amdgcn_s_setprio(0);
                __builtin_amdgcn_sched_barrier(0);
                if (ph == 3) {
                    if (j < 7) asm volatile("s_waitcnt vmcnt(4)" ::: "memory");
                    else       asm volatile("s_waitcnt vmcnt(0)" ::: "memory");
                } else if (ph == 7 && j < 7) {
                    asm volatile("s_waitcnt vmcnt(4)" ::: "memory");
                }
                __builtin_amdgcn_s_barrier();
            }
        }
    }

    const int jr = hi * 4;
    if (tn < 4) {
        // K half -> Kh [bh][kv][128]
        #pragma unroll
        for (int ni = 0; ni < 4; ++ni) {
            int cg = tn * 256 + wn * 64 + ni * 16 + r0;
            float bv = us2f(bias[cg]);
            int h = cg >> 7, d = cg & 127;
            #pragma unroll
            for (int mi = 0; mi < 8; ++mi) {
                #pragma unroll
                for (int j = 0; j < 4; ++j) {
                    int rg = tm * 256 + wm * 128 + mi * 16 + jr + j;
                    int b = rg / 4608, kv = rg - b * 4608;
                    Kh[((long)(b * 8 + h) * 4608 + kv) * 128 + d] = f2us(acc[mi][ni][j] + bv);
                }
            }
        }
    } else {
        // V half -> VTh [bh][128][4608], kv phi-permuted within each 64-block
        #pragma unroll
        for (int ni = 0; ni < 4; ++ni) {
            int cgr = tn * 256 + wn * 64 + ni * 16 + r0;
            float bv = us2f(bias[cgr]);
            int cg = cgr - 1024;
            int h = cg >> 7, d = cg & 127;
            #pragma unroll
            for (int mi = 0; mi < 8; ++mi) {
                int rgb = tm * 256 + wm * 128 + mi * 16 + jr;
                int b = rgb / 4608, kv = rgb - b * 4608;
                int r = kv & 63;
                int P = ((r >> 5) & 1) * 32 + ((r >> 3) & 1) * 16 + ((r >> 2) & 1) * 8
                      + ((r >> 4) & 1) * 4 + (r & 3);
                ushort4 o;
                o.x = f2us(acc[mi][ni][0] + bv);
                o.y = f2us(acc[mi][ni][1] + bv);
                o.z = f2us(acc[mi][ni][2] + bv);
                o.w = f2us(acc[mi][ni][3] + bv);
                *(ushort4*)&VTh[((long)(b * 8 + h) * 128 + d) * 4608 + (kv & ~63) + P] = o;
            }
        }
    }
}

// 3-chunk swapped-operand flash attention (round-10 proven version, NSPLIT=4).
__global__ __launch_bounds__(256, 2)
void attn_kernel7(const unsigned short* __restrict__ Qh, const unsigned short* __restrict__ Kh,
                  const unsigned short* __restrict__ VTh, unsigned short* __restrict__ Opart,
                  float2* __restrict__ Ml)
{
    const int bid = blockIdx.x;
    const int logical = (bid & 7) * 48 + (bid >> 3);   // 384 blocks, XCD-grouped
    const int bhsp = logical / 3;
    const int qt = logical - bhsp * 3;
    const int bh = bhsp >> 2;
    const int sp = bhsp & 3;

    const int tid = threadIdx.x;
    const int lane = tid & 63, wid = tid >> 6;
    const int r0 = lane & 15, hi = lane >> 4;

    __shared__ __align__(16) unsigned short Ks[2][64 * 128];
    __shared__ __align__(16) unsigned short VT[2][128 * 64];

    short8 qf[3][4];
    #pragma unroll
    for (int c = 0; c < 3; ++c) {
        const long qoff = ((long)bh * NTOK + qt * 192 + c * 64 + wid * 16 + r0) * HD + hi * 8;
        #pragma unroll
        for (int kd = 0; kd < 4; ++kd)
            qf[c][kd] = *reinterpret_cast<const short8*>(Qh + qoff + kd * 32);
    }

    f32x4 zz = {0.f, 0.f, 0.f, 0.f};
    f32x4 oacc[3][8];
    #pragma unroll
    for (int c = 0; c < 3; ++c)
        #pragma unroll
        for (int i = 0; i < 8; ++i) oacc[c][i] = zz;
    float mrun[3], lrun[3];
    #pragma unroll
    for (int c = 0; c < 3; ++c) { mrun[c] = -1e30f; lrun[c] = 0.f; }

    int offK[4], offV[4];
    #pragma unroll
    for (int j = 0; j < 4; ++j) {
        offK[j] = (wid * 16 + 4 * j + hi) * 128 + (((lane & 15) ^ ((4 * j + hi) & 7)) << 3);
        offV[j] = (wid * 32 + 8 * j + (lane >> 3)) * KN + (((lane & 7) ^ (lane >> 3)) << 3);
    }
    const unsigned short* kp = Kh + (long)bh * KN * HD + (long)(sp * (KN / NSPLIT)) * HD;
    const unsigned short* vp = VTh + (long)bh * HD * KN + sp * (KN / NSPLIT);

    auto stage = [&](int buf) {
        #pragma unroll
        for (int j = 0; j < 4; ++j) {
            async16(kp + offK[j], &Ks[buf][(wid * 16 + 4 * j) * 128]);
            async16(vp + offV[j], &VT[buf][(wid * 32 + 8 * j) * 64]);
        }
    };

    stage(0);
    for (int kt = 0; kt < NT; ++kt) {
        wait_vm0_barrier();
        if (kt < NT - 1) { kp += 64 * HD; vp += 64; stage((kt + 1) & 1); }
        const unsigned short* Ksb = Ks[kt & 1];
        const unsigned short* VTb = VT[kt & 1];

        f32x4 s[3][4];
        #pragma unroll
        for (int c = 0; c < 3; ++c)
            #pragma unroll
            for (int nb = 0; nb < 4; ++nb) s[c][nb] = zz;
        __builtin_amdgcn_s_setprio(1);
        #pragma unroll
        for (int nb = 0; nb < 4; ++nb) {
            #pragma unroll
            for (int kd = 0; kd < 4; ++kd) {
                short8 kf = *reinterpret_cast<const short8*>(
                    &Ksb[(nb * 16 + r0) * 128 + (((kd * 4 + hi) ^ (r0 & 7)) << 3)]);
                s[0][nb] = __builtin_amdgcn_mfma_f32_16x16x32_bf16(kf, qf[0][kd], s[0][nb], 0, 0, 0);
                s[1][nb] = __builtin_amdgcn_mfma_f32_16x16x32_bf16(kf, qf[1][kd], s[1][nb], 0, 0, 0);
                s[2][nb] = __builtin_amdgcn_mfma_f32_16x16x32_bf16(kf, qf[2][kd], s[2][nb], 0, 0, 0);
            }
        }
        __builtin_amdgcn_s_setprio(0);

        unsigned pk0[3][4], pk1[3][4];
        #pragma unroll
        for (int c = 0; c < 3; ++c) {
            float mt = fmaxf(fmaxf(fmaxf(s[c][0][0], s[c][0][1]), fmaxf(s[c][0][2], s[c][0][3])),
                       fmaxf(fmaxf(fmaxf(s[c][1][0], s[c][1][1]), fmaxf(s[c][1][2], s[c][1][3])),
                       fmaxf(fmaxf(fmaxf(s[c][2][0], s[c][2][1]), fmaxf(s[c][2][2], s[c][2][3])),
                             fmaxf(fmaxf(s[c][3][0], s[c][3][1]), fmaxf(s[c][3][2], s[c][3][3])))));
            if (!__all(mt - mrun[c] <= 8.0f)) {
                float mr = fmaxf(mt, __shfl_xor(mt, 16));
                mr = fmaxf(mr, __shfl_xor(mr, 32));
                float mn = fmaxf(mrun[c], mr);
                float scl = exp2f(mrun[c] - mn);
                mrun[c] = mn;
                lrun[c] *= scl;
                #pragma unroll
                for (int db = 0; db < 8; ++db)
                    #pragma unroll
                    for (int j = 0; j < 4; ++j)
                        oacc[c][db][j] *= scl;
            }
            float rt = 0.f;
            #pragma unroll
            for (int nb = 0; nb < 4; ++nb)
                #pragma unroll
                for (int j = 0; j < 4; ++j) {
                    s[c][nb][j] = exp2f(s[c][nb][j] - mrun[c]);
                    rt += s[c][nb][j];
                }
            lrun[c] += rt;
            #pragma unroll
            for (int nb = 0; nb < 4; ++nb) {
                asm("v_cvt_pk_bf16_f32 %0, %1, %2" : "=v"(pk0[c][nb]) : "v"(s[c][nb][0]), "v"(s[c][nb][1]));
                asm("v_cvt_pk_bf16_f32 %0, %1, %2" : "=v"(pk1[c][nb]) : "v"(s[c][nb][2]), "v"(s[c][nb][3]));
            }
        }

        __builtin_amdgcn_s_setprio(1);
        #pragma unroll
        for (int kd = 0; kd < 2; ++kd) {
            short8 pf[3];
            #pragma unroll
            for (int c = 0; c < 3; ++c) {
                i32x4 fr;
                fr[0] = (int)pk0[c][2 * kd];
                fr[1] = (int)pk1[c][2 * kd];
                fr[2] = (int)pk0[c][2 * kd + 1];
                fr[3] = (int)pk1[c][2 * kd + 1];
                pf[c] = *reinterpret_cast<short8*>(&fr);
            }
            #pragma unroll
            for (int db = 0; db < 8; ++db) {
                short8 vf = *reinterpret_cast<const short8*>(
                    &VTb[(db * 16 + r0) * 64 + (((kd * 4 + hi) ^ (r0 & 7)) << 3)]);
                oacc[0][db] = __builtin_amdgcn_mfma_f32_16x16x32_bf16(vf, pf[0], oacc[0][db], 0, 0, 0);
                oacc[1][db] = __builtin_amdgcn_mfma_f32_16x16x32_bf16(vf, pf[1], oacc[1][db], 0, 0, 0);
                oacc[2][db] = __builtin_amdgcn_mfma_f32_16x16x32_bf16(vf, pf[2], oacc[2][db], 0, 0, 0);
            }
        }
        __builtin_amdgcn_s_setprio(0);
    }

    #pragma unroll
    for (int c = 0; c < 3; ++c) {
        float lr = lrun[c];
        lr += __shfl_xor(lr, 16);
        lr += __shfl_xor(lr, 32);
        const float inv = 1.f / lr;
        const long po = ((long)(sp * 32 + bh) * NTOK + qt * 192 + c * 64 + wid * 16 + r0) * HD;
        #pragma unroll
        for (int db = 0; db < 8; ++db) {
            ushort4 o;
            o.x = f2us(oacc[c][db][0] * inv);
            o.y = f2us(oacc[c][db][1] * inv);
            o.z = f2us(oacc[c][db][2] * inv);
            o.w = f2us(oacc[c][db][3] * inv);
            *(ushort4*)&Opart[po + db * 16 + hi * 4] = o;
        }
        if (lane < 16) {
            const long mo = (long)(sp * 32 + bh) * NTOK + qt * 192 + c * 64 + wid * 16 + r0;
            Ml[mo] = make_float2(mrun[c], lr);
        }
    }
}

// Combine NSPLIT partials -> Ob[(b*576+n)*1024 + h*128 + d]
__global__ __launch_bounds__(256)
void attn_reduce(const unsigned short* __restrict__ Opart, const float2* __restrict__ Ml,
                 unsigned short* __restrict__ Ob)
{
    const int qt = blockIdx.x, bh = blockIdx.y;
    const int t = threadIdx.x;
    const int rl = t >> 2, dc = (t & 3) * 32;
    const int q = qt * 64 + rl;

    float m[NSPLIT], l[NSPLIT];
    float M = -1e30f;
    #pragma unroll
    for (int sp = 0; sp < NSPLIT; ++sp) {
        float2 v = Ml[(long)(sp * 32 + bh) * NTOK + q];
        m[sp] = v.x; l[sp] = v.y;
        M = fmaxf(M, v.x);
    }
    float w[NSPLIT], denom = 0.f;
    #pragma unroll
    for (int sp = 0; sp < NSPLIT; ++sp) {
        w[sp] = l[sp] * exp2f(m[sp] - M);
        denom += w[sp];
    }
    const float inv = 1.f / denom;
    const int b = bh >> 3, h = bh & 7;
    #pragma unroll
    for (int dj = 0; dj < 4; ++dj) {
        float a[8];
        #pragma unroll
        for (int e = 0; e < 8; ++e) a[e] = 0.f;
        #pragma unroll
        for (int sp = 0; sp < NSPLIT; ++sp) {
            short8 v = *reinterpret_cast<const short8*>(
                &Opart[((long)(sp * 32 + bh) * NTOK + q) * HD + dc + dj * 8]);
            #pragma unroll
            for (int e = 0; e < 8; ++e)
                a[e] += w[sp] * us2f((unsigned short)v[e]);
        }
        short8 o;
        #pragma unroll
        for (int e = 0; e < 8; ++e) o[e] = (short)f2us(a[e] * inv);
        *reinterpret_cast<short8*>(&Ob[((long)b * NTOK + q) * 1024 + h * 128 + dc + dj * 8]) = o;
    }
}

// LayerNorm(y)*g + b + vision; output dtype per meta[0]
__global__ __launch_bounds__(256)
void ln2_kernel(const unsigned short* __restrict__ Y, const unsigned short* __restrict__ g,
                const unsigned short* __restrict__ be, const unsigned short* __restrict__ vis,
                void* __restrict__ dout, const int* __restrict__ meta)
{
    const int row = blockIdx.x;
    const int tid = threadIdx.x;
    const int lane = tid & 63, wid = tid >> 6;
    const unsigned short* yr = Y + (long)row * DIM;
    ushort4 raw = reinterpret_cast<const ushort4*>(yr)[tid];
    float v[4];
    v[0] = us2f(raw.x); v[1] = us2f(raw.y); v[2] = us2f(raw.z); v[3] = us2f(raw.w);
    float s1 = 0.f, s2 = 0.f;
    #pragma unroll
    for (int i = 0; i < 4; ++i) { s1 += v[i]; s2 += v[i] * v[i]; }
    #pragma unroll
    for (int off = 1; off < 64; off <<= 1) {
        s1 += __shfl_xor(s1, off);
        s2 += __shfl_xor(s2, off);
    }
    __shared__ float red[2][4];
    if (lane == 0) { red[0][wid] = s1; red[1][wid] = s2; }
    __syncthreads();
    s1 = red[0][0] + red[0][1] + red[0][2] + red[0][3];
    s2 = red[1][0] + red[1][1] + red[1][2] + red[1][3];
    const float mu = s1 * (1.f / DIM);
    const float var = s2 * (1.f / DIM) - mu * mu;
    const float inv = rsqrtf(var + 1e-5f);
    ushort4 gg = reinterpret_cast<const ushort4*>(g)[tid];
    ushort4 bb = reinterpret_cast<const ushort4*>(be)[tid];
    ushort4 vv = reinterpret_cast<const ushort4*>(vis + (long)row * DIM)[tid];
    float o0 = (v[0] - mu) * inv * us2f(gg.x) + us2f(bb.x) + us2f(vv.x);
    float o1 = (v[1] - mu) * inv * us2f(gg.y) + us2f(bb.y) + us2f(vv.y);
    float o2 = (v[2] - mu) * inv * us2f(gg.z) + us2f(bb.z) + us2f(vv.z);
    float o3 = (v[3] - mu) * inv * us2f(gg.w) + us2f(bb.w) + us2f(vv.w);
    if (meta[0]) {
        ushort4 o;
        o.x = f2us(o0); o.y = f2us(o1); o.z = f2us(o2); o.w = f2us(o3);
        reinterpret_cast<ushort4*>((unsigned short*)dout + (long)row * DIM)[tid] = o;
    } else {
        float4 o = make_float4(o0, o1, o2, o3);
        reinterpret_cast<float4*>((float*)dout + (long)row * DIM)[tid] = o;
    }
}

extern "C" void kernel_launch(void* const* d_in, const int* in_sizes, int n_in,
                              void* d_out, int out_size, void* d_ws, size_t ws_size,
                              hipStream_t stream)
{
    // scan_idx (d_in[11]) unused: all 8 scans are bijections on the 576 cells and
    // softmax over the full K*N key axis (K,V share row order) is permutation-
    // invariant per direction block -> gather elided.
    unsigned long long w = (unsigned long long)d_ws;
    int* meta = (int*)w; w += 256;

    const int cidx[10] = {0, 2, 3, 4, 5, 6, 7, 8, 9, 10};
    const long csz[10] = {
        (long)NB * NTOK * DIM,  // vision
        (long)KDIR * DIM,       // dirb
        3L * DIM * DIM,         // inW
        3L * DIM,               // inB
        (long)DIM * DIM,        // outW
        DIM,                    // outB
        (long)DIM * DIM,        // finW
        DIM, DIM, DIM           // finB, lng, lnb
    };
    unsigned short* cv[10];
    for (int i = 0; i < 10; ++i) {
        cv[i] = (unsigned short*)w;
        w += (csz[i] * 2 + 255) & ~255ULL;
    }
    unsigned short* dWT = (unsigned short*)w; w += (long)KDIR * DIM * DIM * 2;

    const size_t big = (size_t)NB * KDIR * NTOK * DIM * 2;   // 37.75 MB
    const size_t sml = (size_t)NB * NTOK * DIM * 2;          // 4.72 MB
    unsigned short* dirs = (unsigned short*)w; w += big;     // aliased as Opart later
    unsigned short* Kh   = (unsigned short*)w; w += big;
    unsigned short* VTh  = (unsigned short*)w; w += big;
    unsigned short* Qh   = (unsigned short*)w; w += sml;
    unsigned short* Ob   = (unsigned short*)w; w += sml;
    unsigned short* Fu   = (unsigned short*)w; w += sml;
    unsigned short* Y2   = (unsigned short*)w; w += sml;
    float2* Ml = (float2*)w; w += (long)NSPLIT * 32 * NTOK * sizeof(float2);
    unsigned short* Opart = dirs;   // dirs dead after KV GEMM; 18.9MB < 37.75MB

    const unsigned short* vision = cv[0];
    const unsigned short* dirb = cv[1];
    const unsigned short* inW = cv[2];
    const unsigned short* inB = cv[3];
    const unsigned short* outW = cv[4];
    const unsigned short* outB = cv[5];
    const unsigned short* finW = cv[6];
    const unsigned short* finB = cv[7];
    const unsigned short* lng = cv[8];
    const unsigned short* lnbt = cv[9];

    dim3 blk(256, 1, 1);

    // 0. dtype detect
    detect_kernel<<<dim3(1), dim3(64), 0, stream>>>((const unsigned int*)d_in[1], meta);

    // 1. single fused conversion launch (+ transposed dirW)
    ConvJobs J;
    int bacc = 0;
    for (int i = 0; i < 10; ++i) {
        J.src[i] = d_in[cidx[i]];
        J.dst[i] = cv[i];
        J.n4[i] = (int)(csz[i] / 4);
        J.bstart[i] = bacc;
        bacc += (int)((csz[i] / 4 + 1023) / 1024);
    }
    conv_all<<<dim3(bacc), blk, 0, stream>>>(J, meta);
    transpose_conv<<<dim3(1024, KDIR), blk, 0, stream>>>(d_in[1], dWT, meta);

    // 2. merged dirs(z<8)+Q(z==8, pre-scaled) GEMM: A=vision, M=2304
    gemm_glds<6, 8, 128, 128><<<dim3(18 * 8, 9), blk, 0, stream>>>(
        vision, dWT, dirb, dirs, inW, inB, Qh, NB * NTOK, (long)DIM * DIM, DIM);

    // 3. fused K+V GEMM, 8-phase 256^2 ring-staged pipeline
    gemm_kv8p<<<dim3(72 * 8), dim3(512), 0, stream>>>(
        dirs, inW + DIM * DIM, inB + DIM, Kh, VTh);

    // 4. 3-chunk KV-split flash attention -> Opart (aliases dirs) + Ml
    attn_kernel7<<<dim3(3 * 32 * NSPLIT), blk, 0, stream>>>(Qh, Kh, VTh, Opart, Ml);

    // 5. combine partials -> Ob [b,n,h*128+d]
    attn_reduce<<<dim3(9, 32), blk, 0, stream>>>(Opart, Ml, Ob);

    // 6. fused = Ob @ out_proj^T + b   (64x64 tile: 576 blocks)
    gemm_glds<0, 16, 64, 64><<<dim3(36 * 16, 1), blk, 0, stream>>>(
        Ob, outW, outB, Fu, nullptr, nullptr, nullptr, NB * NTOK, 0L, 0L);

    // 7. y = fused @ fin^T + b
    gemm_glds<0, 16, 64, 64><<<dim3(36 * 16, 1), blk, 0, stream>>>(
        Fu, finW, finB, Y2, nullptr, nullptr, nullptr, NB * NTOK, 0L, 0L);

    // 8. LayerNorm + residual -> d_out
    ln2_kernel<<<dim3(NB * NTOK), blk, 0, stream>>>(Y2, lng, lnbt, vision, d_out, meta);
}

// Round 15
// 331.543 us; speedup vs baseline: 1.1039x; 1.0379x over previous
//
#include <hip/hip_runtime.h>
#include <hip/hip_bf16.h>

typedef __attribute__((ext_vector_type(8))) short short8;
typedef __attribute__((ext_vector_type(4))) float f32x4;
typedef __attribute__((ext_vector_type(4))) int i32x4;

#define NTOK 576
#define DIM  1024
#define NB   4
#define NH   8
#define HD   128
#define KDIR 8
#define KN   4608
#define NSPLIT 4
#define NT 18                 // KN/NSPLIT/64

__device__ __forceinline__ float us2f(unsigned short u) {
    unsigned int x = ((unsigned int)u) << 16;
    return __uint_as_float(x);
}
__device__ __forceinline__ unsigned short f2us(float f) {
    unsigned int x = __float_as_uint(f);
    unsigned int r = x + 0x7fffu + ((x >> 16) & 1u);
    return (unsigned short)(r >> 16);
}

typedef __attribute__((address_space(3))) unsigned int lds_uint;
typedef const __attribute__((address_space(1))) unsigned int glb_uint;
__device__ __forceinline__ void async16(const unsigned short* g, unsigned short* l) {
    __builtin_amdgcn_global_load_lds((glb_uint*)g, (lds_uint*)l, 16, 0, 0);
}
__device__ __forceinline__ void wait_vm0_barrier() {
    asm volatile("s_waitcnt vmcnt(0)" ::: "memory");
    __builtin_amdgcn_s_barrier();
    __builtin_amdgcn_sched_barrier(0);
}

// meta[0] = 1 if device buffers are bf16, 0 if f32
__global__ void detect_kernel(const unsigned int* __restrict__ src, int* meta)
{
    if (threadIdx.x == 0) {
        int cnt = 0;
        for (int i = 0; i < 256; ++i) {
            unsigned u = src[(long)i * 16384] & 0xFFFFu;
            unsigned e = (u >> 7) & 0xFFu;
            cnt += (e >= 90 && e <= 150) ? 1 : 0;
        }
        meta[0] = (cnt >= 192) ? 1 : 0;
    }
}

// All 10 small conversions in one launch.
struct ConvJobs {
    const void* src[10];
    unsigned short* dst[10];
    int n4[10];
    int bstart[10];
};
__global__ __launch_bounds__(256)
void conv_all(ConvJobs J, const int* __restrict__ meta)
{
    const int b = blockIdx.x;
    int ji = 0;
    #pragma unroll
    for (int i = 1; i < 10; ++i) if (b >= J.bstart[i]) ji = i;
    const long base = (long)(b - J.bstart[ji]) * 1024 + threadIdx.x;
    const long n4 = J.n4[ji];
    if (meta[0]) {
        const ushort4* s = (const ushort4*)J.src[ji];
        ushort4* d = (ushort4*)J.dst[ji];
        #pragma unroll
        for (int t = 0; t < 4; ++t) {
            long i = base + t * 256;
            if (i < n4) d[i] = s[i];
        }
    } else {
        const float4* s = (const float4*)J.src[ji];
        ushort4* d = (ushort4*)J.dst[ji];
        #pragma unroll
        for (int t = 0; t < 4; ++t) {
            long i = base + t * 256;
            if (i < n4) {
                float4 v = s[i];
                ushort4 o;
                o.x = f2us(v.x); o.y = f2us(v.y); o.z = f2us(v.z); o.w = f2us(v.w);
                d[i] = o;
            }
        }
    }
}

// dirW [8][1024 d][1024 e] -> dWT [8][1024 e][1024 d]
__global__ __launch_bounds__(256)
void transpose_conv(const void* __restrict__ src, unsigned short* __restrict__ dst,
                    const int* __restrict__ meta)
{
    const int k = blockIdx.y;
    const int ty = blockIdx.x >> 5, tx = blockIdx.x & 31;
    const int d0 = ty * 32, e0 = tx * 32;
    __shared__ float tl[32][33];
    const int t = threadIdx.x;
    const int row = t >> 3, c4 = (t & 7) * 4;
    const long sbase = ((long)k * 1024 + d0 + row) * 1024 + e0 + c4;
    if (meta[0]) {
        const unsigned short* s = (const unsigned short*)src;
        ushort4 v = *(const ushort4*)(s + sbase);
        tl[row][c4+0] = us2f(v.x); tl[row][c4+1] = us2f(v.y);
        tl[row][c4+2] = us2f(v.z); tl[row][c4+3] = us2f(v.w);
    } else {
        const float* s = (const float*)src;
        float4 v = *(const float4*)(s + sbase);
        tl[row][c4+0] = v.x; tl[row][c4+1] = v.y;
        tl[row][c4+2] = v.z; tl[row][c4+3] = v.w;
    }
    __syncthreads();
    ushort4 o;
    o.x = f2us(tl[c4+0][row]); o.y = f2us(tl[c4+1][row]);
    o.z = f2us(tl[c4+2][row]); o.w = f2us(tl[c4+3][row]);
    *(ushort4*)(dst + ((long)k * 1024 + e0 + row) * 1024 + d0 + c4) = o;
}

// C = A[M x 1024] @ B^T + bias. Tile BM x BN, BK=64, SINGLE-buffer glds staging
// (m97 structure: 32KB LDS -> 5 blocks/CU; implicit wave-level overlap hides drain).
// MODE: 0 row-major C; 5 fused KV (cg<1024 -> Kh [bh][kv][128], else VTh [bh][128][4608]
//       with kv phi-permuted within each 64-block for the attn b128 PV reads);
//       6 merged dirs(z<8)+Q(z==8, pre-scaled by 1/sqrt(128)*log2e)
template<int MODE, int TN, int BM, int BN>
__global__ __launch_bounds__(256)
void gemm_glds(const unsigned short* __restrict__ A, const unsigned short* __restrict__ Bw,
               const unsigned short* __restrict__ bias, unsigned short* __restrict__ C,
               const unsigned short* __restrict__ B2, const unsigned short* __restrict__ bias2,
               unsigned short* __restrict__ C2,
               int M, long bStride, long biasStride)
{
    constexpr int MI = BM / 32, NI = BN / 32;
    const int z = blockIdx.y;
    const unsigned short* Bb;
    const unsigned short* Gb;
    if constexpr (MODE == 6) {
        Bb = (z < 8) ? Bw + (long)z * bStride : B2;
        Gb = (z < 8) ? bias + (long)z * biasStride : bias2;
    } else {
        Bb = Bw + (long)z * bStride;
        Gb = bias + (long)z * biasStride;
    }
    const int tm = blockIdx.x / TN;
    const int tn = blockIdx.x % TN;

    __shared__ __align__(16) unsigned short As[BM * 64];
    __shared__ __align__(16) unsigned short Bs[BN * 64];

    const int tid = threadIdx.x, lane = tid & 63, wid = tid >> 6;
    const int wm = wid >> 1, wn = wid & 1;
    const int r0 = lane & 15, hi = lane >> 4;
    const int lr = lane >> 3;
    const int lg = lane & 7;

    f32x4 zz = {0.f, 0.f, 0.f, 0.f};
    f32x4 acc[MI][NI];
    #pragma unroll
    for (int i = 0; i < MI; ++i)
        #pragma unroll
        for (int j = 0; j < NI; ++j) acc[i][j] = zz;

    const int sgc = ((lg ^ (lr & 7)) << 3);

    for (int k0 = 0; k0 < 1024; k0 += 64) {
        #pragma unroll
        for (int j = 0; j < BM / 32; ++j) {
            int rb = wid * (BM / 4) + j * 8;
            async16(A + (long)(tm * BM + rb + lr) * 1024 + k0 + sgc, &As[rb * 64]);
        }
        #pragma unroll
        for (int j = 0; j < BN / 32; ++j) {
            int rb = wid * (BN / 4) + j * 8;
            async16(Bb + (long)(tn * BN + rb + lr) * 1024 + k0 + sgc, &Bs[rb * 64]);
        }
        __syncthreads();
        __builtin_amdgcn_s_setprio(1);
        #pragma unroll
        for (int kd = 0; kd < 2; ++kd) {
            const int pg = ((kd * 4 + hi) ^ (r0 & 7)) << 3;
            short8 af[MI], bfr[NI];
            #pragma unroll
            for (int mi = 0; mi < MI; ++mi)
                af[mi] = *reinterpret_cast<const short8*>(&As[(wm * (BM/2) + mi * 16 + r0) * 64 + pg]);
            #pragma unroll
            for (int ni = 0; ni < NI; ++ni)
                bfr[ni] = *reinterpret_cast<const short8*>(&Bs[(wn * (BN/2) + ni * 16 + r0) * 64 + pg]);
            #pragma unroll
            for (int mi = 0; mi < MI; ++mi)
                #pragma unroll
                for (int ni = 0; ni < NI; ++ni)
                    acc[mi][ni] = __builtin_amdgcn_mfma_f32_16x16x32_bf16(af[mi], bfr[ni], acc[mi][ni], 0, 0, 0);
        }
        __builtin_amdgcn_s_setprio(0);
        __syncthreads();
    }

    const float QSCL = 0.08838834764831845f * 1.4426950408889634f;
    const int jr = hi * 4;
    #pragma unroll
    for (int ni = 0; ni < NI; ++ni) {
        int cg = tn * BN + wn * (BN/2) + ni * 16 + r0;
        float bv = us2f(Gb[cg]);
        if constexpr (MODE == 5) {
            if (cg >= 1024) {
                int cg2 = cg - 1024;
                int h = cg2 >> 7, d = cg2 & 127;
                #pragma unroll
                for (int mi = 0; mi < MI; ++mi) {
                    int rgb = tm * BM + wm * (BM/2) + mi * 16 + jr;
                    int b = rgb / 4608, kv = rgb - b * 4608;
                    // phi-permute kv within its 64-block: P = [b5][b3][b2][b4][b1b0]
                    int r = kv & 63;
                    int P = ((r >> 5) & 1) * 32 + ((r >> 3) & 1) * 16 + ((r >> 2) & 1) * 8
                          + ((r >> 4) & 1) * 4 + (r & 3);
                    ushort4 o;
                    o.x = f2us(acc[mi][ni][0] + bv);
                    o.y = f2us(acc[mi][ni][1] + bv);
                    o.z = f2us(acc[mi][ni][2] + bv);
                    o.w = f2us(acc[mi][ni][3] + bv);
                    *(ushort4*)&C2[((long)(b * 8 + h) * 128 + d) * 4608 + (kv & ~63) + P] = o;
                }
                continue;
            }
        }
        #pragma unroll
        for (int mi = 0; mi < MI; ++mi) {
            #pragma unroll
            for (int j = 0; j < 4; ++j) {
                int rg = tm * BM + wm * (BM/2) + mi * 16 + jr + j;
                float val = acc[mi][ni][j] + bv;
                if constexpr (MODE == 0) {
                    C[(long)rg * 1024 + cg] = f2us(val);
                } else if constexpr (MODE == 5) {
                    int b = rg / 4608, kv = rg - b * 4608;
                    int h = cg >> 7, d = cg & 127;
                    C[((long)(b * 8 + h) * 4608 + kv) * 128 + d] = f2us(val);
                } else {  // MODE 6
                    int b = rg / 576, n = rg - b * 576;
                    if (z == 8) {
                        int h = cg >> 7, d = cg & 127;
                        C2[((long)(b * 8 + h) * 576 + n) * 128 + d] = f2us(val * QSCL);
                    } else {
                        C[((long)b * 4608 + (long)z * 576 + n) * 1024 + cg] = f2us(val);
                    }
                }
            }
        }
    }
}

// 3-chunk swapped-operand flash attention: 192 q rows per block (48/wave).
// Each K/V LDS b128 read feeds 3 MFMAs (one per q-chunk) -> 3x LDS amortization.
// V^T global is phi-permuted so the PV A-fragment is one contiguous b128 and the
// P B-fragment is lane-local (zero shuffles, zero extra conflicts).
__global__ __launch_bounds__(256, 2)
void attn_kernel7(const unsigned short* __restrict__ Qh, const unsigned short* __restrict__ Kh,
                  const unsigned short* __restrict__ VTh, unsigned short* __restrict__ Opart,
                  float2* __restrict__ Ml)
{
    const int bid = blockIdx.x;
    const int logical = (bid & 7) * 48 + (bid >> 3);   // 384 blocks, XCD-grouped
    const int bhsp = logical / 3;
    const int qt = logical - bhsp * 3;
    const int bh = bhsp >> 2;
    const int sp = bhsp & 3;

    const int tid = threadIdx.x;
    const int lane = tid & 63, wid = tid >> 6;
    const int r0 = lane & 15, hi = lane >> 4;

    __shared__ __align__(16) unsigned short Ks[2][64 * 128];
    __shared__ __align__(16) unsigned short VT[2][128 * 64];

    short8 qf[3][4];
    #pragma unroll
    for (int c = 0; c < 3; ++c) {
        const long qoff = ((long)bh * NTOK + qt * 192 + c * 64 + wid * 16 + r0) * HD + hi * 8;
        #pragma unroll
        for (int kd = 0; kd < 4; ++kd)
            qf[c][kd] = *reinterpret_cast<const short8*>(Qh + qoff + kd * 32);
    }

    f32x4 zz = {0.f, 0.f, 0.f, 0.f};
    f32x4 oacc[3][8];
    #pragma unroll
    for (int c = 0; c < 3; ++c)
        #pragma unroll
        for (int i = 0; i < 8; ++i) oacc[c][i] = zz;
    float mrun[3], lrun[3];
    #pragma unroll
    for (int c = 0; c < 3; ++c) { mrun[c] = -1e30f; lrun[c] = 0.f; }

    int offK[4], offV[4];
    #pragma unroll
    for (int j = 0; j < 4; ++j) {
        offK[j] = (wid * 16 + 4 * j + hi) * 128 + (((lane & 15) ^ ((4 * j + hi) & 7)) << 3);
        offV[j] = (wid * 32 + 8 * j + (lane >> 3)) * KN + (((lane & 7) ^ (lane >> 3)) << 3);
    }
    const unsigned short* kp = Kh + (long)bh * KN * HD + (long)(sp * (KN / NSPLIT)) * HD;
    const unsigned short* vp = VTh + (long)bh * HD * KN + sp * (KN / NSPLIT);

    auto stage = [&](int buf) {
        #pragma unroll
        for (int j = 0; j < 4; ++j) {
            async16(kp + offK[j], &Ks[buf][(wid * 16 + 4 * j) * 128]);
            async16(vp + offV[j], &VT[buf][(wid * 32 + 8 * j) * 64]);
        }
    };

    stage(0);
    for (int kt = 0; kt < NT; ++kt) {
        wait_vm0_barrier();
        if (kt < NT - 1) { kp += 64 * HD; vp += 64; stage((kt + 1) & 1); }
        const unsigned short* Ksb = Ks[kt & 1];
        const unsigned short* VTb = VT[kt & 1];

        f32x4 s[3][4];
        #pragma unroll
        for (int c = 0; c < 3; ++c)
            #pragma unroll
            for (int nb = 0; nb < 4; ++nb) s[c][nb] = zz;
        __builtin_amdgcn_s_setprio(1);
        #pragma unroll
        for (int nb = 0; nb < 4; ++nb) {
            #pragma unroll
            for (int kd = 0; kd < 4; ++kd) {
                short8 kf = *reinterpret_cast<const short8*>(
                    &Ksb[(nb * 16 + r0) * 128 + (((kd * 4 + hi) ^ (r0 & 7)) << 3)]);
                s[0][nb] = __builtin_amdgcn_mfma_f32_16x16x32_bf16(kf, qf[0][kd], s[0][nb], 0, 0, 0);
                s[1][nb] = __builtin_amdgcn_mfma_f32_16x16x32_bf16(kf, qf[1][kd], s[1][nb], 0, 0, 0);
                s[2][nb] = __builtin_amdgcn_mfma_f32_16x16x32_bf16(kf, qf[2][kd], s[2][nb], 0, 0, 0);
            }
        }
        __builtin_amdgcn_s_setprio(0);

        unsigned pk0[3][4], pk1[3][4];
        #pragma unroll
        for (int c = 0; c < 3; ++c) {
            float mt = fmaxf(fmaxf(fmaxf(s[c][0][0], s[c][0][1]), fmaxf(s[c][0][2], s[c][0][3])),
                       fmaxf(fmaxf(fmaxf(s[c][1][0], s[c][1][1]), fmaxf(s[c][1][2], s[c][1][3])),
                       fmaxf(fmaxf(fmaxf(s[c][2][0], s[c][2][1]), fmaxf(s[c][2][2], s[c][2][3])),
                             fmaxf(fmaxf(s[c][3][0], s[c][3][1]), fmaxf(s[c][3][2], s[c][3][3])))));
            if (!__all(mt - mrun[c] <= 8.0f)) {
                float mr = fmaxf(mt, __shfl_xor(mt, 16));
                mr = fmaxf(mr, __shfl_xor(mr, 32));
                float mn = fmaxf(mrun[c], mr);
                float scl = exp2f(mrun[c] - mn);
                mrun[c] = mn;
                lrun[c] *= scl;
                #pragma unroll
                for (int db = 0; db < 8; ++db)
                    #pragma unroll
                    for (int j = 0; j < 4; ++j)
                        oacc[c][db][j] *= scl;
            }
            float rt = 0.f;
            #pragma unroll
            for (int nb = 0; nb < 4; ++nb)
                #pragma unroll
                for (int j = 0; j < 4; ++j) {
                    s[c][nb][j] = exp2f(s[c][nb][j] - mrun[c]);
                    rt += s[c][nb][j];
                }
            lrun[c] += rt;
            #pragma unroll
            for (int nb = 0; nb < 4; ++nb) {
                asm("v_cvt_pk_bf16_f32 %0, %1, %2" : "=v"(pk0[c][nb]) : "v"(s[c][nb][0]), "v"(s[c][nb][1]));
                asm("v_cvt_pk_bf16_f32 %0, %1, %2" : "=v"(pk1[c][nb]) : "v"(s[c][nb][2]), "v"(s[c][nb][3]));
            }
        }

        __builtin_amdgcn_s_setprio(1);
        #pragma unroll
        for (int kd = 0; kd < 2; ++kd) {
            short8 pf[3];
            #pragma unroll
            for (int c = 0; c < 3; ++c) {
                i32x4 fr;
                fr[0] = (int)pk0[c][2 * kd];
                fr[1] = (int)pk1[c][2 * kd];
                fr[2] = (int)pk0[c][2 * kd + 1];
                fr[3] = (int)pk1[c][2 * kd + 1];
                pf[c] = *reinterpret_cast<short8*>(&fr);
            }
            #pragma unroll
            for (int db = 0; db < 8; ++db) {
                short8 vf = *reinterpret_cast<const short8*>(
                    &VTb[(db * 16 + r0) * 64 + (((kd * 4 + hi) ^ (r0 & 7)) << 3)]);
                oacc[0][db] = __builtin_amdgcn_mfma_f32_16x16x32_bf16(vf, pf[0], oacc[0][db], 0, 0, 0);
                oacc[1][db] = __builtin_amdgcn_mfma_f32_16x16x32_bf16(vf, pf[1], oacc[1][db], 0, 0, 0);
                oacc[2][db] = __builtin_amdgcn_mfma_f32_16x16x32_bf16(vf, pf[2], oacc[2][db], 0, 0, 0);
            }
        }
        __builtin_amdgcn_s_setprio(0);
    }

    #pragma unroll
    for (int c = 0; c < 3; ++c) {
        float lr = lrun[c];
        lr += __shfl_xor(lr, 16);
        lr += __shfl_xor(lr, 32);
        const float inv = 1.f / lr;
        const long po = ((long)(sp * 32 + bh) * NTOK + qt * 192 + c * 64 + wid * 16 + r0) * HD;
        #pragma unroll
        for (int db = 0; db < 8; ++db) {
            ushort4 o;
            o.x = f2us(oacc[c][db][0] * inv);
            o.y = f2us(oacc[c][db][1] * inv);
            o.z = f2us(oacc[c][db][2] * inv);
            o.w = f2us(oacc[c][db][3] * inv);
            *(ushort4*)&Opart[po + db * 16 + hi * 4] = o;
        }
        if (lane < 16) {
            const long mo = (long)(sp * 32 + bh) * NTOK + qt * 192 + c * 64 + wid * 16 + r0;
            Ml[mo] = make_float2(mrun[c], lr);   // log2 domain
        }
    }
}

// Combine NSPLIT partials -> Ob[(b*576+n)*1024 + h*128 + d]
__global__ __launch_bounds__(256)
void attn_reduce(const unsigned short* __restrict__ Opart, const float2* __restrict__ Ml,
                 unsigned short* __restrict__ Ob)
{
    const int qt = blockIdx.x, bh = blockIdx.y;
    const int t = threadIdx.x;
    const int rl = t >> 2, dc = (t & 3) * 32;
    const int q = qt * 64 + rl;

    float m[NSPLIT], l[NSPLIT];
    float M = -1e30f;
    #pragma unroll
    for (int sp = 0; sp < NSPLIT; ++sp) {
        float2 v = Ml[(long)(sp * 32 + bh) * NTOK + q];
        m[sp] = v.x; l[sp] = v.y;
        M = fmaxf(M, v.x);
    }
    float w[NSPLIT], denom = 0.f;
    #pragma unroll
    for (int sp = 0; sp < NSPLIT; ++sp) {
        w[sp] = l[sp] * exp2f(m[sp] - M);
        denom += w[sp];
    }
    const float inv = 1.f / denom;
    const int b = bh >> 3, h = bh & 7;
    #pragma unroll
    for (int dj = 0; dj < 4; ++dj) {
        float a[8];
        #pragma unroll
        for (int e = 0; e < 8; ++e) a[e] = 0.f;
        #pragma unroll
        for (int sp = 0; sp < NSPLIT; ++sp) {
            short8 v = *reinterpret_cast<const short8*>(
                &Opart[((long)(sp * 32 + bh) * NTOK + q) * HD + dc + dj * 8]);
            #pragma unroll
            for (int e = 0; e < 8; ++e)
                a[e] += w[sp] * us2f((unsigned short)v[e]);
        }
        short8 o;
        #pragma unroll
        for (int e = 0; e < 8; ++e) o[e] = (short)f2us(a[e] * inv);
        *reinterpret_cast<short8*>(&Ob[((long)b * NTOK + q) * 1024 + h * 128 + dc + dj * 8]) = o;
    }
}

// LayerNorm(y)*g + b + vision; output dtype per meta[0]
__global__ __launch_bounds__(256)
void ln2_kernel(const unsigned short* __restrict__ Y, const unsigned short* __restrict__ g,
                const unsigned short* __restrict__ be, const unsigned short* __restrict__ vis,
                void* __restrict__ dout, const int* __restrict__ meta)
{
    const int row = blockIdx.x;
    const int tid = threadIdx.x;
    const int lane = tid & 63, wid = tid >> 6;
    const unsigned short* yr = Y + (long)row * DIM;
    ushort4 raw = reinterpret_cast<const ushort4*>(yr)[tid];
    float v[4];
    v[0] = us2f(raw.x); v[1] = us2f(raw.y); v[2] = us2f(raw.z); v[3] = us2f(raw.w);
    float s1 = 0.f, s2 = 0.f;
    #pragma unroll
    for (int i = 0; i < 4; ++i) { s1 += v[i]; s2 += v[i] * v[i]; }
    #pragma unroll
    for (int off = 1; off < 64; off <<= 1) {
        s1 += __shfl_xor(s1, off);
        s2 += __shfl_xor(s2, off);
    }
    __shared__ float red[2][4];
    if (lane == 0) { red[0][wid] = s1; red[1][wid] = s2; }
    __syncthreads();
    s1 = red[0][0] + red[0][1] + red[0][2] + red[0][3];
    s2 = red[1][0] + red[1][1] + red[1][2] + red[1][3];
    const float mu = s1 * (1.f / DIM);
    const float var = s2 * (1.f / DIM) - mu * mu;
    const float inv = rsqrtf(var + 1e-5f);
    ushort4 gg = reinterpret_cast<const ushort4*>(g)[tid];
    ushort4 bb = reinterpret_cast<const ushort4*>(be)[tid];
    ushort4 vv = reinterpret_cast<const ushort4*>(vis + (long)row * DIM)[tid];
    float o0 = (v[0] - mu) * inv * us2f(gg.x) + us2f(bb.x) + us2f(vv.x);
    float o1 = (v[1] - mu) * inv * us2f(gg.y) + us2f(bb.y) + us2f(vv.y);
    float o2 = (v[2] - mu) * inv * us2f(gg.z) + us2f(bb.z) + us2f(vv.z);
    float o3 = (v[3] - mu) * inv * us2f(gg.w) + us2f(bb.w) + us2f(vv.w);
    if (meta[0]) {
        ushort4 o;
        o.x = f2us(o0); o.y = f2us(o1); o.z = f2us(o2); o.w = f2us(o3);
        reinterpret_cast<ushort4*>((unsigned short*)dout + (long)row * DIM)[tid] = o;
    } else {
        float4 o = make_float4(o0, o1, o2, o3);
        reinterpret_cast<float4*>((float*)dout + (long)row * DIM)[tid] = o;
    }
}

extern "C" void kernel_launch(void* const* d_in, const int* in_sizes, int n_in,
                              void* d_out, int out_size, void* d_ws, size_t ws_size,
                              hipStream_t stream)
{
    // scan_idx (d_in[11]) unused: all 8 scans are bijections on the 576 cells and
    // softmax over the full K*N key axis (K,V share row order) is permutation-
    // invariant per direction block -> gather elided.
    unsigned long long w = (unsigned long long)d_ws;
    int* meta = (int*)w; w += 256;

    const int cidx[10] = {0, 2, 3, 4, 5, 6, 7, 8, 9, 10};
    const long csz[10] = {
        (long)NB * NTOK * DIM,  // vision
        (long)KDIR * DIM,       // dirb
        3L * DIM * DIM,         // inW
        3L * DIM,               // inB
        (long)DIM * DIM,        // outW
        DIM,                    // outB
        (long)DIM * DIM,        // finW
        DIM, DIM, DIM           // finB, lng, lnb
    };
    unsigned short* cv[10];
    for (int i = 0; i < 10; ++i) {
        cv[i] = (unsigned short*)w;
        w += (csz[i] * 2 + 255) & ~255ULL;
    }
    unsigned short* dWT = (unsigned short*)w; w += (long)KDIR * DIM * DIM * 2;

    const size_t big = (size_t)NB * KDIR * NTOK * DIM * 2;   // 37.75 MB
    const size_t sml = (size_t)NB * NTOK * DIM * 2;          // 4.72 MB
    unsigned short* dirs = (unsigned short*)w; w += big;     // aliased as Opart later
    unsigned short* Kh   = (unsigned short*)w; w += big;
    unsigned short* VTh  = (unsigned short*)w; w += big;
    unsigned short* Qh   = (unsigned short*)w; w += sml;
    unsigned short* Ob   = (unsigned short*)w; w += sml;
    unsigned short* Fu   = (unsigned short*)w; w += sml;
    unsigned short* Y2   = (unsigned short*)w; w += sml;
    float2* Ml = (float2*)w; w += (long)NSPLIT * 32 * NTOK * sizeof(float2);
    unsigned short* Opart = dirs;   // dirs dead after KV GEMM; 18.9MB < 37.75MB

    const unsigned short* vision = cv[0];
    const unsigned short* dirb = cv[1];
    const unsigned short* inW = cv[2];
    const unsigned short* inB = cv[3];
    const unsigned short* outW = cv[4];
    const unsigned short* outB = cv[5];
    const unsigned short* finW = cv[6];
    const unsigned short* finB = cv[7];
    const unsigned short* lng = cv[8];
    const unsigned short* lnbt = cv[9];

    dim3 blk(256, 1, 1);

    // 0. dtype detect
    detect_kernel<<<dim3(1), dim3(64), 0, stream>>>((const unsigned int*)d_in[1], meta);

    // 1. single fused conversion launch (+ transposed dirW)
    ConvJobs J;
    int bacc = 0;
    for (int i = 0; i < 10; ++i) {
        J.src[i] = d_in[cidx[i]];
        J.dst[i] = cv[i];
        J.n4[i] = (int)(csz[i] / 4);
        J.bstart[i] = bacc;
        bacc += (int)((csz[i] / 4 + 1023) / 1024);
    }
    conv_all<<<dim3(bacc), blk, 0, stream>>>(J, meta);
    transpose_conv<<<dim3(1024, KDIR), blk, 0, stream>>>(d_in[1], dWT, meta);

    // 2. merged dirs(z<8)+Q(z==8, pre-scaled) GEMM: A=vision, M=2304
    gemm_glds<6, 8, 128, 128><<<dim3(18 * 8, 9), blk, 0, stream>>>(
        vision, dWT, dirb, dirs, inW, inB, Qh, NB * NTOK, (long)DIM * DIM, DIM);

    // 3. fused K+V GEMM (wk||wv contiguous): K->Kh, V->VTh (phi-permuted)
    gemm_glds<5, 16, 128, 128><<<dim3(144 * 16, 1), blk, 0, stream>>>(
        dirs, inW + DIM * DIM, inB + DIM, Kh, nullptr, nullptr, VTh, NB * KN, 0L, 0L);

    // 4. 3-chunk KV-split flash attention -> Opart (aliases dirs) + Ml
    attn_kernel7<<<dim3(3 * 32 * NSPLIT), blk, 0, stream>>>(Qh, Kh, VTh, Opart, Ml);

    // 5. combine partials -> Ob [b,n,h*128+d]
    attn_reduce<<<dim3(9, 32), blk, 0, stream>>>(Opart, Ml, Ob);

    // 6. fused = Ob @ out_proj^T + b   (64x64 tile: 576 blocks)
    gemm_glds<0, 16, 64, 64><<<dim3(36 * 16, 1), blk, 0, stream>>>(
        Ob, outW, outB, Fu, nullptr, nullptr, nullptr, NB * NTOK, 0L, 0L);

    // 7. y = fused @ fin^T + b
    gemm_glds<0, 16, 64, 64><<<dim3(36 * 16, 1), blk, 0, stream>>>(
        Fu, finW, finB, Y2, nullptr, nullptr, nullptr, NB * NTOK, 0L, 0L);

    // 8. LayerNorm + residual -> d_out
    ln2_kernel<<<dim3(NB * NTOK), blk, 0, stream>>>(Y2, lng, lnbt, vision, d_out, meta);
}